// Round 13
// baseline (312.139 us; speedup 1.0000x reference)
//
#include <hip/hip_runtime.h>
#include <math.h>

#define L_SEQ 256
#define TILE 16
#define NSEG 16

typedef __attribute__((ext_vector_type(2))) float f32x2;
typedef __attribute__((ext_vector_type(4))) float f32x4;
typedef __attribute__((ext_vector_type(8))) _Float16 f16x8;
typedef __attribute__((ext_vector_type(2))) _Float16 f16x2;

__device__ __forceinline__ f32x2 fma2(f32x2 a, f32x2 b, f32x2 c) {
    return __builtin_elementwise_fma(a, b, c);
}
__device__ __forceinline__ f32x2 splat2(float x) { f32x2 v = {x, x}; return v; }
__device__ __forceinline__ float silu_f(float x) { return x / (1.f + __expf(-x)); }
__device__ __forceinline__ float sp2_f(float x) {
    return log2f(1.f + exp2f(x * 1.44269504f)) * 0.69314718f;
}

// ---- prep (one launch, 7 blocks):
//  blocks 0..4: WT[160][128] f16 = [x_proj[:,:4]@dt_w | x_proj[:,4:36]]^T
//  block 5:     W2[256][32] f16 (conv+expansion+in_proj folded) + bias2
//  block 6:     sflag = all channels have A[n] == -(n+1)
__global__ __launch_bounds__(256)
void k_prep(const float* __restrict__ exp_w, const float* __restrict__ exp_b,
            const float* __restrict__ in_proj_w, const float* __restrict__ x_proj_w,
            const float* __restrict__ dt_w,
            const float* __restrict__ conv_w, const float* __restrict__ conv_b,
            const float* __restrict__ A_log,
            _Float16* __restrict__ WT, _Float16* __restrict__ W2,
            float* __restrict__ bias2, int* __restrict__ sflag)
{
    const int t = threadIdx.x, blk = blockIdx.x;
    if (blk < 5) {
        const int base = blk * 4096;
        for (int i = base + t; i < base + 4096; i += 256) {
            const int row = i >> 7, k = i & 127;
            float v;
            if (row < 128) {
                v = x_proj_w[k * 36 + 0] * dt_w[row]
                  + x_proj_w[k * 36 + 1] * dt_w[128 + row]
                  + x_proj_w[k * 36 + 2] * dt_w[256 + row]
                  + x_proj_w[k * 36 + 3] * dt_w[384 + row];
            } else {
                v = x_proj_w[k * 36 + 4 + (row - 128)];
            }
            WT[i] = (_Float16)v;
        }
    } else if (blk == 5) {
        // thread t<128 -> xc channel d=t ; t>=128 -> z channel d=t-128
        const int d = t & 127;
        const int col = (t < 128) ? d : (128 + d);
        float w0 = 0, w1 = 0, w2 = 0, w3 = 0, bb = 0;
        for (int k = 0; k < 64; ++k) {
            float w = in_proj_w[k * 256 + col];
            w0 = fmaf(exp_w[k], w, w0);
            w1 = fmaf(exp_w[64 + k], w, w1);
            w2 = fmaf(exp_w[128 + k], w, w2);
            w3 = fmaf(exp_w[192 + k], w, w3);
            bb = fmaf(exp_b[k], w, bb);
        }
        const float wx[4] = {w0, w1, w2, w3};
        if (t < 128) {
            for (int j = 0; j < 32; ++j) {
                float v = 0.f;
                if (j < 16)      v = conv_w[d * 4 + (j >> 2)] * wx[j & 3];
                else if (j < 20) v = conv_w[d * 4 + (j - 16)] * bb;
                W2[d * 32 + j] = (_Float16)v;
            }
            bias2[d] = conv_b[d];
        } else {
            for (int j = 0; j < 32; ++j) {
                float v = 0.f;
                if (j >= 12 && j < 16) v = wx[j - 12];
                else if (j == 19)      v = bb;
                W2[(128 + d) * 32 + j] = (_Float16)v;
            }
        }
    } else {
        __shared__ int ok;
        if (t == 0) ok = 1;
        __syncthreads();
        bool good = true;
        for (int i = t; i < 2048; i += 256) {
            float a = -__expf(A_log[i]);
            good = good && (fabsf(a + (float)((i & 15) + 1)) < 1e-3f);
        }
        if (!good) atomicAnd(&ok, 0);
        __syncthreads();
        if (t == 0) sflag[0] = ok;
    }
}

// ---- fused Mamba: grid = B*16 blocks x 256 threads, one 16-step segment each ----
__global__ __launch_bounds__(256, 6)
void mamba_seg(const float* __restrict__ reads,
               const _Float16* __restrict__ WT, const _Float16* __restrict__ W2,
               const float* __restrict__ bias2, const float* __restrict__ dt_b,
               const float* __restrict__ A_log, const float* __restrict__ D_skip,
               const int* __restrict__ sflag,
               f16x2* __restrict__ Qg, f16x2* __restrict__ Pg, f16x2* __restrict__ Kg,
               float* __restrict__ GS, float* __restrict__ CZ, float* __restrict__ SL,
               int Bn)
{
    const int bx = blockIdx.x;
    const int b = bx >> 4, sidx = bx & 15;
    const int l_off = sidx * TILE;
    const int t = threadIdx.x;
    const int dd = t >> 1, g = t & 1;          // phase E: channel, state-half

    __shared__ __align__(16) _Float16 XC[TILE * 136];  // conv out (silu), fp16
    __shared__ __align__(16) float    BC[TILE * 32];   // B(16)|C(16) per step
    __shared__ _Float16               ZS[TILE * 128];  // silu(z)
    __shared__ _Float16               DE[TILE * 128];  // delta

    const float dskip = D_skip[dd];
    const bool structured = (sflag[0] != 0);

    const int lane = t & 63, wv = t >> 6;
    const int fcol = lane & 15, kq = lane >> 4, rbase = kq * 4;

    const float4* rdv = (const float4*)(reads + (size_t)b * L_SEQ * 4);

    // ---- phase A: A-fragment built in registers (no LDS stage, no barrier) ----
    f16x8 af;
    {
        const int r0 = l_off + fcol - 3;
        if (kq < 2) {
            const int ra = r0 + kq * 2;
            const float4 z4 = make_float4(0.f, 0.f, 0.f, 0.f);
            const float4 va = (ra >= 0)     ? rdv[ra]     : z4;
            const float4 vb = (ra + 1 >= 0) ? rdv[ra + 1] : z4;
            af[0] = (_Float16)va.x; af[1] = (_Float16)va.y;
            af[2] = (_Float16)va.z; af[3] = (_Float16)va.w;
            af[4] = (_Float16)vb.x; af[5] = (_Float16)vb.y;
            af[6] = (_Float16)vb.z; af[7] = (_Float16)vb.w;
        } else if (kq == 2) {
            af[0] = (_Float16)((r0 >= 0)     ? 1.f : 0.f);
            af[1] = (_Float16)((r0 + 1 >= 0) ? 1.f : 0.f);
            af[2] = (_Float16)((r0 + 2 >= 0) ? 1.f : 0.f);
            af[3] = (_Float16)((r0 + 3 >= 0) ? 1.f : 0.f);
            af[4] = af[5] = af[6] = af[7] = (_Float16)0.f;
        } else {
#pragma unroll
            for (int e = 0; e < 8; ++e) af[e] = (_Float16)0.f;
        }
    }
    // MFMA [16 x 256] = F @ W2^T ; silu -> XC, ZS   (af reused across 4 tasks)
#pragma unroll
    for (int i = 0; i < 4; ++i) {
        const int n = wv + 4 * i;              // 16 tasks over 4 waves
        f16x8 bf = *(const f16x8*)&W2[(n * 16 + fcol) * 32 + kq * 8];
        f32x4 acc = {0.f, 0.f, 0.f, 0.f};
        acc = __builtin_amdgcn_mfma_f32_16x16x32_f16(af, bf, acc, 0, 0, 0);
        if (n < 8) {
            const int ch = n * 16 + fcol;
            const float bv = bias2[ch];
#pragma unroll
            for (int r = 0; r < 4; ++r)
                XC[(rbase + r) * 136 + ch] = (_Float16)silu_f(acc[r] + bv);
        } else {
            const int ch = (n - 8) * 16 + fcol;
#pragma unroll
            for (int r = 0; r < 4; ++r)
                ZS[(rbase + r) * 128 + ch] = (_Float16)silu_f(acc[r]);
        }
    }
    __syncthreads();

    // ---- phase C: MFMA [16 x 160] = XC[16x128] @ WT^T -> DE (softplus) | BC ----
#pragma unroll
    for (int i = 0; i < 3; ++i) {
        const int n = wv + 4 * i;              // 10 tasks over 4 waves
        if (n < 10) {
            f32x4 acc = {0.f, 0.f, 0.f, 0.f};
#pragma unroll
            for (int ks = 0; ks < 4; ++ks) {
                const int ko = ks * 32 + kq * 8;
                f16x8 xa = *(const f16x8*)&XC[fcol * 136 + ko];
                f16x8 bf = *(const f16x8*)&WT[(n * 16 + fcol) * 128 + ko];
                acc = __builtin_amdgcn_mfma_f32_16x16x32_f16(xa, bf, acc, 0, 0, 0);
            }
            if (n < 8) {
                const int ch = n * 16 + fcol;
                const float db = dt_b[ch];
#pragma unroll
                for (int r = 0; r < 4; ++r)
                    DE[(rbase + r) * 128 + ch] = (_Float16)sp2_f(acc[r] + db);
            } else {
                const int jb = (n - 8) * 16 + fcol;
#pragma unroll
                for (int r = 0; r < 4; ++r)
                    BC[(rbase + r) * 32 + jb] = acc[r];
            }
        }
    }
    __syncthreads();

    // ---- phase E: 16-step serial scan; 2 lanes/channel, all waves active ----
    f32x2 h2[4], P2[4], K2[4];
#pragma unroll
    for (int k = 0; k < 4; ++k) { h2[k] = splat2(0.f); P2[k] = splat2(1.f); K2[k] = splat2(0.f); }
    float gsum = 0.f;
    {
        auto scan_loop = [&](bool needpk) {
#pragma unroll 4
            for (int l = 0; l < TILE; ++l) {
                const float de = (float)DE[l * 128 + dd];
                const float zs = (float)ZS[l * 128 + dd];
                const float xc = (float)XC[l * 136 + dd];
                const float du = de * xc;
                f32x2 E2[4];
                if (structured) {              // states 8g+1..8g+8: powers of r
                    const float r  = exp2f(de * -1.44269504f);
                    const float r2 = r * r;
                    const float r4 = r2 * r2;
                    const float t1 = g ? (r4 * r4 * r) : r;   // r^(8g+1), no 2nd exp2
                    E2[0] = (f32x2){t1, t1 * r};
                    const f32x2 r2s = splat2(r2);
                    E2[1] = E2[0] * r2s;
                    E2[2] = E2[1] * r2s;
                    E2[3] = E2[2] * r2s;
                } else {                       // cold generic path
#pragma unroll
                    for (int k = 0; k < 4; ++k) {
                        float e0 = exp2f(de * (-__expf(A_log[dd * 16 + g * 8 + 2 * k])) * 1.44269504f);
                        float e1 = exp2f(de * (-__expf(A_log[dd * 16 + g * 8 + 2 * k + 1])) * 1.44269504f);
                        E2[k] = (f32x2){e0, e1};
                    }
                }
                const float4 Bq0 = *(const float4*)&BC[l * 32 + g * 8];
                const float4 Bq1 = *(const float4*)&BC[l * 32 + g * 8 + 4];
                const float4 Cq0 = *(const float4*)&BC[l * 32 + 16 + g * 8];
                const float4 Cq1 = *(const float4*)&BC[l * 32 + 16 + g * 8 + 4];
                const f32x2 B2[4] = {{Bq0.x, Bq0.y}, {Bq0.z, Bq0.w}, {Bq1.x, Bq1.y}, {Bq1.z, Bq1.w}};
                const f32x2 C2[4] = {{Cq0.x, Cq0.y}, {Cq0.z, Cq0.w}, {Cq1.x, Cq1.y}, {Cq1.z, Cq1.w}};
                const f32x2 dus = splat2(du), zss = splat2(zs);
                f32x2 yp2 = splat2(0.f);
#pragma unroll
                for (int k = 0; k < 4; ++k) {
                    h2[k] = fma2(E2[k], h2[k], dus * B2[k]);
                    yp2 = fma2(h2[k], C2[k], yp2);
                    if (needpk) {
                        P2[k] = P2[k] * E2[k];
                        K2[k] = fma2(zss, C2[k] * P2[k], K2[k]);
                    }
                }
                float yp = yp2.x + yp2.y;
                const float y = yp + __shfl_xor(yp, 1);
                gsum += fmaf(xc, dskip, y) * zs;
            }
        };
        if (sidx == 0) scan_loop(false);
        else           scan_loop(true);
    }

    // ---- segment summary writeout (LDS still holds the tile) ----
    {
        const size_t sb = (size_t)sidx * Bn + b;
#pragma unroll
        for (int k = 0; k < 4; ++k) {
            const size_t o = (sb * 8 + g * 4 + k) * 128 + dd;   // pair p = g*4+k
            Qg[o] = (f16x2){(_Float16)h2[k].x, (_Float16)h2[k].y};
            if (sidx != 0) {
                Pg[o] = (f16x2){(_Float16)P2[k].x, (_Float16)P2[k].y};
                Kg[o] = (f16x2){(_Float16)K2[k].x, (_Float16)K2[k].y};
            }
        }
        if (g == 0) GS[sb * 128 + dd] = gsum;
        if (sidx == NSEG - 1) {
            const float zs_last = (float)ZS[(TILE - 1) * 128 + dd];
            const float xc_last = (float)XC[(TILE - 1) * 136 + dd];
#pragma unroll
            for (int k = 0; k < 8; ++k)
                CZ[((size_t)b * 16 + g * 8 + k) * 128 + dd] =
                    zs_last * BC[(TILE - 1) * 32 + 16 + g * 8 + k];
            if (g == 0) SL[(size_t)b * 128 + dd] = zs_last * xc_last * dskip;
        }
    }
}

// ---- stitch: chain segment summaries, out_proj, fused keys ----
template<int NS>
__global__ __launch_bounds__(128)
void stitch(const f16x2* __restrict__ Qg, const f16x2* __restrict__ Pg,
            const f16x2* __restrict__ Kg, const float* __restrict__ GS,
            const float* __restrict__ CZ, const float* __restrict__ SL,
            const float* __restrict__ out_proj_w,
            const float* __restrict__ k_w, const float* __restrict__ k_b,
            float* __restrict__ pooled, float* __restrict__ keysT, int Bn)
{
    const int b = blockIdx.x, d = threadIdx.x;
    __shared__ float gb[256];
    __shared__ float pl[128];

    float h[16];
    float gsum = GS[(size_t)b * 128 + d];          // s = 0: h0 = 0
#pragma unroll
    for (int p = 0; p < 8; ++p) {
        f16x2 q = Qg[((size_t)b * 8 + p) * 128 + d];
        h[2 * p] = (float)q[0]; h[2 * p + 1] = (float)q[1];
    }
#pragma unroll
    for (int s = 1; s < NS; ++s) {
        const size_t sb = (size_t)s * Bn + b;
        gsum += GS[sb * 128 + d];
        float corr = 0.f;
#pragma unroll
        for (int p = 0; p < 8; ++p) {
            const size_t o = (sb * 8 + p) * 128 + d;
            f16x2 qv = Qg[o], pv = Pg[o], kv = Kg[o];
            corr = fmaf((float)kv[0], h[2 * p], corr);
            corr = fmaf((float)kv[1], h[2 * p + 1], corr);
            h[2 * p]     = fmaf((float)pv[0], h[2 * p],     (float)qv[0]);
            h[2 * p + 1] = fmaf((float)pv[1], h[2 * p + 1], (float)qv[1]);
        }
        gsum += corr;
    }
    float glast = SL[(size_t)b * 128 + d];
#pragma unroll
    for (int n = 0; n < 16; ++n)
        glast = fmaf(CZ[((size_t)b * 16 + n) * 128 + d], h[n], glast);

    gb[d] = gsum * (1.f / (float)L_SEQ);
    gb[128 + d] = glast;
    __syncthreads();
    {
        const int half = d >> 6, oc = d & 63;
        const float* gbp = &gb[half * 128];
        float s = 0.f;
#pragma unroll 16
        for (int i = 0; i < 128; ++i) s = fmaf(gbp[i], out_proj_w[i * 64 + oc], s);
        pooled[(size_t)b * 128 + d] = s;
        pl[d] = s;
    }
    __syncthreads();
    if (d < 64) {
        float s = k_b[d];
#pragma unroll 16
        for (int i = 0; i < 128; ++i) s = fmaf(pl[i], k_w[i * 64 + d], s);
        keysT[(size_t)d * Bn + b] = s;
    }
}

// ---- qk: 2 queries per block; float4 keysT loads ----
__global__ __launch_bounds__(128)
void qk_kernel(const float* __restrict__ pooled, const int* __restrict__ idx,
               const float* __restrict__ q_w, const float* __restrict__ q_b,
               const float* __restrict__ keysT, float* __restrict__ out, int B, int N)
{
    const int n0 = blockIdx.x * 2, t = threadIdx.x;
    const int n1 = n0 + 1;
    const bool has1 = (n1 < N);
    __shared__ float p0[128], p1[128];
    __shared__ float q0[64], q1[64];
    const int bi0 = idx[n0];
    const int bi1 = has1 ? idx[n1] : bi0;
    p0[t] = pooled[(size_t)bi0 * 128 + t];
    p1[t] = pooled[(size_t)bi1 * 128 + t];
    __syncthreads();
    if (t < 64) {
        float s = q_b[t];
#pragma unroll
        for (int i = 0; i < 128; ++i) s = fmaf(p0[i], q_w[i * 64 + t], s);
        q0[t] = s;
    } else {
        const int tt = t - 64;
        float s = q_b[tt];
#pragma unroll
        for (int i = 0; i < 128; ++i) s = fmaf(p1[i], q_w[i * 64 + tt], s);
        q1[tt] = s;
    }
    __syncthreads();
    for (int m0 = t * 4; m0 < B; m0 += 512) {
        f32x4 a0 = {0.f, 0.f, 0.f, 0.f}, a1 = {0.f, 0.f, 0.f, 0.f};
#pragma unroll 8
        for (int i = 0; i < 64; ++i) {
            const float4 kv = *(const float4*)&keysT[(size_t)i * B + m0];
            const float qa = q0[i], qb = q1[i];
            a0[0] = fmaf(qa, kv.x, a0[0]); a0[1] = fmaf(qa, kv.y, a0[1]);
            a0[2] = fmaf(qa, kv.z, a0[2]); a0[3] = fmaf(qa, kv.w, a0[3]);
            a1[0] = fmaf(qb, kv.x, a1[0]); a1[1] = fmaf(qb, kv.y, a1[1]);
            a1[2] = fmaf(qb, kv.z, a1[2]); a1[3] = fmaf(qb, kv.w, a1[3]);
        }
        *(f32x4*)&out[(size_t)n0 * B + m0] = a0;
        if (has1) *(f32x4*)&out[(size_t)n1 * B + m0] = a1;
    }
}

// ============================ LAUNCH ============================

extern "C" void kernel_launch(void* const* d_in, const int* in_sizes, int n_in,
                              void* d_out, int out_size, void* d_ws, size_t ws_size,
                              hipStream_t stream)
{
    const float* reads      = (const float*)d_in[0];
    const int*   idx        = (const int*)d_in[1];
    const float* exp_w      = (const float*)d_in[2];
    const float* exp_b      = (const float*)d_in[3];
    const float* in_proj_w  = (const float*)d_in[4];
    const float* conv_w     = (const float*)d_in[5];
    const float* conv_b     = (const float*)d_in[6];
    const float* x_proj_w   = (const float*)d_in[7];
    const float* dt_w       = (const float*)d_in[8];
    const float* dt_b       = (const float*)d_in[9];
    const float* A_log      = (const float*)d_in[10];
    const float* D_skip     = (const float*)d_in[11];
    const float* out_proj_w = (const float*)d_in[12];
    const float* q_w        = (const float*)d_in[13];
    const float* q_b        = (const float*)d_in[14];
    const float* k_w        = (const float*)d_in[15];
    const float* k_b        = (const float*)d_in[16];

    const int B = in_sizes[0] / (L_SEQ * 4);
    const int N = in_sizes[1];

    char* wsb = (char*)d_ws;
    size_t off = 0;
    auto alloc = [&](size_t bytes) {
        size_t o = off;
        off = (off + bytes + 255) & ~(size_t)255;
        return o;
    };

    float*     pooled = (float*)(wsb + alloc((size_t)B * 128 * 4));
    float*     keysT  = (float*)(wsb + alloc((size_t)B * 64 * 4));
    _Float16*  WT     = (_Float16*)(wsb + alloc(160 * 128 * 2));
    _Float16*  W2     = (_Float16*)(wsb + alloc(256 * 32 * 2));
    float*     bias2  = (float*)(wsb + alloc(128 * 4));
    int*       sflag  = (int*)(wsb + alloc(256));

    const size_t pairs = (size_t)B * NSEG * 8 * 128;
    f16x2* Qg = (f16x2*)(wsb + alloc(pairs * 4));
    f16x2* Pg = (f16x2*)(wsb + alloc(pairs * 4));
    f16x2* Kg = (f16x2*)(wsb + alloc(pairs * 4));
    float* GS = (float*)(wsb + alloc((size_t)B * NSEG * 128 * 4));
    float* CZ = (float*)(wsb + alloc((size_t)B * 16 * 128 * 4));
    float* SL = (float*)(wsb + alloc((size_t)B * 128 * 4));

    k_prep<<<7, 256, 0, stream>>>(exp_w, exp_b, in_proj_w, x_proj_w, dt_w,
                                  conv_w, conv_b, A_log, WT, W2, bias2, sflag);
    mamba_seg<<<B * NSEG, 256, 0, stream>>>(reads, WT, W2, bias2, dt_b,
                                            A_log, D_skip, sflag, Qg, Pg, Kg,
                                            GS, CZ, SL, B);
    stitch<NSEG><<<B, 128, 0, stream>>>(Qg, Pg, Kg, GS, CZ, SL, out_proj_w, k_w, k_b,
                                        pooled, keysT, B);
    qk_kernel<<<(N + 1) / 2, 128, 0, stream>>>(pooled, idx, q_w, q_b, keysT,
                                               (float*)d_out, B, N);
}

// Round 14
// 130.549 us; speedup vs baseline: 2.3910x; 2.3910x over previous
//
#include <hip/hip_runtime.h>
#include <math.h>

#define L_SEQ 256
#define TILE 16
#define NSEG 16

typedef __attribute__((ext_vector_type(2))) float f32x2;
typedef __attribute__((ext_vector_type(4))) float f32x4;
typedef __attribute__((ext_vector_type(8))) _Float16 f16x8;
typedef __attribute__((ext_vector_type(2))) _Float16 f16x2;

__device__ __forceinline__ f32x2 fma2(f32x2 a, f32x2 b, f32x2 c) {
    return __builtin_elementwise_fma(a, b, c);
}
__device__ __forceinline__ f32x2 splat2(float x) { f32x2 v = {x, x}; return v; }
__device__ __forceinline__ float silu_f(float x) { return x / (1.f + __expf(-x)); }
__device__ __forceinline__ float sp2_f(float x) {
    return log2f(1.f + exp2f(x * 1.44269504f)) * 0.69314718f;
}

// ---- prep (one launch, 7 blocks):
//  blocks 0..4: WT[160][128] f16 = [x_proj[:,:4]@dt_w | x_proj[:,4:36]]^T
//  block 5:     W2[256][32] f16 (conv+expansion+in_proj folded) + bias2
//  block 6:     sflag = all channels have A[n] == -(n+1)
__global__ __launch_bounds__(256)
void k_prep(const float* __restrict__ exp_w, const float* __restrict__ exp_b,
            const float* __restrict__ in_proj_w, const float* __restrict__ x_proj_w,
            const float* __restrict__ dt_w,
            const float* __restrict__ conv_w, const float* __restrict__ conv_b,
            const float* __restrict__ A_log,
            _Float16* __restrict__ WT, _Float16* __restrict__ W2,
            float* __restrict__ bias2, int* __restrict__ sflag)
{
    const int t = threadIdx.x, blk = blockIdx.x;
    if (blk < 5) {
        const int base = blk * 4096;
        for (int i = base + t; i < base + 4096; i += 256) {
            const int row = i >> 7, k = i & 127;
            float v;
            if (row < 128) {
                v = x_proj_w[k * 36 + 0] * dt_w[row]
                  + x_proj_w[k * 36 + 1] * dt_w[128 + row]
                  + x_proj_w[k * 36 + 2] * dt_w[256 + row]
                  + x_proj_w[k * 36 + 3] * dt_w[384 + row];
            } else {
                v = x_proj_w[k * 36 + 4 + (row - 128)];
            }
            WT[i] = (_Float16)v;
        }
    } else if (blk == 5) {
        // thread t<128 -> xc channel d=t ; t>=128 -> z channel d=t-128
        const int d = t & 127;
        const int col = (t < 128) ? d : (128 + d);
        float w0 = 0, w1 = 0, w2 = 0, w3 = 0, bb = 0;
        for (int k = 0; k < 64; ++k) {
            float w = in_proj_w[k * 256 + col];
            w0 = fmaf(exp_w[k], w, w0);
            w1 = fmaf(exp_w[64 + k], w, w1);
            w2 = fmaf(exp_w[128 + k], w, w2);
            w3 = fmaf(exp_w[192 + k], w, w3);
            bb = fmaf(exp_b[k], w, bb);
        }
        const float wx[4] = {w0, w1, w2, w3};
        if (t < 128) {
            for (int j = 0; j < 32; ++j) {
                float v = 0.f;
                if (j < 16)      v = conv_w[d * 4 + (j >> 2)] * wx[j & 3];
                else if (j < 20) v = conv_w[d * 4 + (j - 16)] * bb;
                W2[d * 32 + j] = (_Float16)v;
            }
            bias2[d] = conv_b[d];
        } else {
            for (int j = 0; j < 32; ++j) {
                float v = 0.f;
                if (j >= 12 && j < 16) v = wx[j - 12];
                else if (j == 19)      v = bb;
                W2[(128 + d) * 32 + j] = (_Float16)v;
            }
        }
    } else {
        __shared__ int ok;
        if (t == 0) ok = 1;
        __syncthreads();
        bool good = true;
        for (int i = t; i < 2048; i += 256) {
            float a = -__expf(A_log[i]);
            good = good && (fabsf(a + (float)((i & 15) + 1)) < 1e-3f);
        }
        if (!good) atomicAnd(&ok, 0);
        __syncthreads();
        if (t == 0) sflag[0] = ok;
    }
}

// ---- fused Mamba: grid = B*16 blocks x 256 threads, one 16-step segment each ----
// R12 structure (F staged in LDS, no scan unroll) + single-exp2 power tree + sflag.
__global__ __launch_bounds__(256, 6)
void mamba_seg(const float* __restrict__ reads,
               const _Float16* __restrict__ WT, const _Float16* __restrict__ W2,
               const float* __restrict__ bias2, const float* __restrict__ dt_b,
               const float* __restrict__ A_log, const float* __restrict__ D_skip,
               const int* __restrict__ sflag,
               f16x2* __restrict__ Qg, f16x2* __restrict__ Pg, f16x2* __restrict__ Kg,
               float* __restrict__ GS, float* __restrict__ CZ, float* __restrict__ SL,
               int Bn)
{
    const int bx = blockIdx.x;
    const int b = bx >> 4, sidx = bx & 15;
    const int l_off = sidx * TILE;
    const int t = threadIdx.x;
    const int dd = t >> 1, g = t & 1;          // phase E: channel, state-half

    __shared__ __align__(16) _Float16 F[TILE * 40];    // features, K-padded
    __shared__ __align__(16) _Float16 XC[TILE * 136];  // conv out (silu), fp16
    __shared__ __align__(16) float    BC[TILE * 32];   // B(16)|C(16) per step
    __shared__ _Float16               ZS[TILE * 128];  // silu(z)
    __shared__ _Float16               DE[TILE * 128];  // delta

    const float dskip = D_skip[dd];
    const bool structured = (sflag[0] != 0);

    // ---- build F[16][40]: taps(16) | bias indicators(4) | pad ----
    for (int i = t; i < TILE * 40; i += 256) {
        const int l = i / 40, j = i - l * 40;
        _Float16 v = (_Float16)0.f;
        if (j < 16) {
            const int row = l_off + l - 3 + (j >> 2);
            if (row >= 0) v = (_Float16)reads[((size_t)b * L_SEQ + row) * 4 + (j & 3)];
        } else if (j < 20) {
            v = (l_off + l - 3 + (j - 16) >= 0) ? (_Float16)1.f : (_Float16)0.f;
        }
        F[i] = v;
    }
    __syncthreads();

    const int lane = t & 63, wv = t >> 6;
    const int fcol = lane & 15, kq = lane >> 4, rbase = kq * 4;

    // ---- phase A: MFMA [16 x 256] = F[16x32] @ W2^T ; silu -> XC, ZS ----
#pragma unroll
    for (int i = 0; i < 4; ++i) {
        const int n = wv + 4 * i;              // 16 tasks over 4 waves
        f16x8 af = *(const f16x8*)&F[fcol * 40 + kq * 8];
        f16x8 bf = *(const f16x8*)&W2[(n * 16 + fcol) * 32 + kq * 8];
        f32x4 acc = {0.f, 0.f, 0.f, 0.f};
        acc = __builtin_amdgcn_mfma_f32_16x16x32_f16(af, bf, acc, 0, 0, 0);
        if (n < 8) {
            const int ch = n * 16 + fcol;
            const float bv = bias2[ch];
#pragma unroll
            for (int r = 0; r < 4; ++r)
                XC[(rbase + r) * 136 + ch] = (_Float16)silu_f(acc[r] + bv);
        } else {
            const int ch = (n - 8) * 16 + fcol;
#pragma unroll
            for (int r = 0; r < 4; ++r)
                ZS[(rbase + r) * 128 + ch] = (_Float16)silu_f(acc[r]);
        }
    }
    __syncthreads();

    // ---- phase C: MFMA [16 x 160] = XC[16x128] @ WT^T -> DE (softplus) | BC ----
#pragma unroll
    for (int i = 0; i < 3; ++i) {
        const int n = wv + 4 * i;              // 10 tasks over 4 waves
        if (n < 10) {
            f32x4 acc = {0.f, 0.f, 0.f, 0.f};
#pragma unroll
            for (int ks = 0; ks < 4; ++ks) {
                const int ko = ks * 32 + kq * 8;
                f16x8 xa = *(const f16x8*)&XC[fcol * 136 + ko];
                f16x8 bf = *(const f16x8*)&WT[(n * 16 + fcol) * 128 + ko];
                acc = __builtin_amdgcn_mfma_f32_16x16x32_f16(xa, bf, acc, 0, 0, 0);
            }
            if (n < 8) {
                const int ch = n * 16 + fcol;
                const float db = dt_b[ch];
#pragma unroll
                for (int r = 0; r < 4; ++r)
                    DE[(rbase + r) * 128 + ch] = (_Float16)sp2_f(acc[r] + db);
            } else {
                const int jb = (n - 8) * 16 + fcol;
#pragma unroll
                for (int r = 0; r < 4; ++r)
                    BC[(rbase + r) * 32 + jb] = acc[r];
            }
        }
    }
    __syncthreads();

    // ---- phase E: 16-step serial scan; 2 lanes/channel, all waves active ----
    f32x2 h2[4], P2[4], K2[4];
#pragma unroll
    for (int k = 0; k < 4; ++k) { h2[k] = splat2(0.f); P2[k] = splat2(1.f); K2[k] = splat2(0.f); }
    float gsum = 0.f;
    {
        auto scan_loop = [&](bool needpk) {
            for (int l = 0; l < TILE; ++l) {
                const float de = (float)DE[l * 128 + dd];
                const float zs = (float)ZS[l * 128 + dd];
                const float xc = (float)XC[l * 136 + dd];
                const float du = de * xc;
                f32x2 E2[4];
                if (structured) {              // states 8g+1..8g+8: powers of r
                    const float r  = exp2f(de * -1.44269504f);
                    const float r2 = r * r;
                    const float r4 = r2 * r2;
                    const float t1 = g ? (r4 * r4 * r) : r;   // r^(8g+1), muls only
                    E2[0] = (f32x2){t1, t1 * r};
                    const f32x2 r2s = splat2(r2);
                    E2[1] = E2[0] * r2s;
                    E2[2] = E2[1] * r2s;
                    E2[3] = E2[2] * r2s;
                } else {                       // cold generic path
#pragma unroll
                    for (int k = 0; k < 4; ++k) {
                        float e0 = exp2f(de * (-__expf(A_log[dd * 16 + g * 8 + 2 * k])) * 1.44269504f);
                        float e1 = exp2f(de * (-__expf(A_log[dd * 16 + g * 8 + 2 * k + 1])) * 1.44269504f);
                        E2[k] = (f32x2){e0, e1};
                    }
                }
                const float4 Bq0 = *(const float4*)&BC[l * 32 + g * 8];
                const float4 Bq1 = *(const float4*)&BC[l * 32 + g * 8 + 4];
                const float4 Cq0 = *(const float4*)&BC[l * 32 + 16 + g * 8];
                const float4 Cq1 = *(const float4*)&BC[l * 32 + 16 + g * 8 + 4];
                const f32x2 B2[4] = {{Bq0.x, Bq0.y}, {Bq0.z, Bq0.w}, {Bq1.x, Bq1.y}, {Bq1.z, Bq1.w}};
                const f32x2 C2[4] = {{Cq0.x, Cq0.y}, {Cq0.z, Cq0.w}, {Cq1.x, Cq1.y}, {Cq1.z, Cq1.w}};
                const f32x2 dus = splat2(du), zss = splat2(zs);
                f32x2 yp2 = splat2(0.f);
#pragma unroll
                for (int k = 0; k < 4; ++k) {
                    h2[k] = fma2(E2[k], h2[k], dus * B2[k]);
                    yp2 = fma2(h2[k], C2[k], yp2);
                    if (needpk) {
                        P2[k] = P2[k] * E2[k];
                        K2[k] = fma2(zss, C2[k] * P2[k], K2[k]);
                    }
                }
                float yp = yp2.x + yp2.y;
                const float y = yp + __shfl_xor(yp, 1);
                gsum += fmaf(xc, dskip, y) * zs;
            }
        };
        if (sidx == 0) scan_loop(false);
        else           scan_loop(true);
    }

    // ---- segment summary writeout (LDS still holds the tile) ----
    {
        const size_t sb = (size_t)sidx * Bn + b;
#pragma unroll
        for (int k = 0; k < 4; ++k) {
            const size_t o = (sb * 8 + g * 4 + k) * 128 + dd;   // pair p = g*4+k
            Qg[o] = (f16x2){(_Float16)h2[k].x, (_Float16)h2[k].y};
            if (sidx != 0) {
                Pg[o] = (f16x2){(_Float16)P2[k].x, (_Float16)P2[k].y};
                Kg[o] = (f16x2){(_Float16)K2[k].x, (_Float16)K2[k].y};
            }
        }
        if (g == 0) GS[sb * 128 + dd] = gsum;
        if (sidx == NSEG - 1) {
            const float zs_last = (float)ZS[(TILE - 1) * 128 + dd];
            const float xc_last = (float)XC[(TILE - 1) * 136 + dd];
#pragma unroll
            for (int k = 0; k < 8; ++k)
                CZ[((size_t)b * 16 + g * 8 + k) * 128 + dd] =
                    zs_last * BC[(TILE - 1) * 32 + 16 + g * 8 + k];
            if (g == 0) SL[(size_t)b * 128 + dd] = zs_last * xc_last * dskip;
        }
    }
}

// ---- stitch: chain segment summaries, out_proj, fused keys ----
template<int NS>
__global__ __launch_bounds__(128)
void stitch(const f16x2* __restrict__ Qg, const f16x2* __restrict__ Pg,
            const f16x2* __restrict__ Kg, const float* __restrict__ GS,
            const float* __restrict__ CZ, const float* __restrict__ SL,
            const float* __restrict__ out_proj_w,
            const float* __restrict__ k_w, const float* __restrict__ k_b,
            float* __restrict__ pooled, float* __restrict__ keysT, int Bn)
{
    const int b = blockIdx.x, d = threadIdx.x;
    __shared__ float gb[256];
    __shared__ float pl[128];

    float h[16];
    float gsum = GS[(size_t)b * 128 + d];          // s = 0: h0 = 0
#pragma unroll
    for (int p = 0; p < 8; ++p) {
        f16x2 q = Qg[((size_t)b * 8 + p) * 128 + d];
        h[2 * p] = (float)q[0]; h[2 * p + 1] = (float)q[1];
    }
#pragma unroll
    for (int s = 1; s < NS; ++s) {
        const size_t sb = (size_t)s * Bn + b;
        gsum += GS[sb * 128 + d];
        float corr = 0.f;
#pragma unroll
        for (int p = 0; p < 8; ++p) {
            const size_t o = (sb * 8 + p) * 128 + d;
            f16x2 qv = Qg[o], pv = Pg[o], kv = Kg[o];
            corr = fmaf((float)kv[0], h[2 * p], corr);
            corr = fmaf((float)kv[1], h[2 * p + 1], corr);
            h[2 * p]     = fmaf((float)pv[0], h[2 * p],     (float)qv[0]);
            h[2 * p + 1] = fmaf((float)pv[1], h[2 * p + 1], (float)qv[1]);
        }
        gsum += corr;
    }
    float glast = SL[(size_t)b * 128 + d];
#pragma unroll
    for (int n = 0; n < 16; ++n)
        glast = fmaf(CZ[((size_t)b * 16 + n) * 128 + d], h[n], glast);

    gb[d] = gsum * (1.f / (float)L_SEQ);
    gb[128 + d] = glast;
    __syncthreads();
    {
        const int half = d >> 6, oc = d & 63;
        const float* gbp = &gb[half * 128];
        float s = 0.f;
#pragma unroll 16
        for (int i = 0; i < 128; ++i) s = fmaf(gbp[i], out_proj_w[i * 64 + oc], s);
        pooled[(size_t)b * 128 + d] = s;
        pl[d] = s;
    }
    __syncthreads();
    if (d < 64) {
        float s = k_b[d];
#pragma unroll 16
        for (int i = 0; i < 128; ++i) s = fmaf(pl[i], k_w[i * 64 + d], s);
        keysT[(size_t)d * Bn + b] = s;
    }
}

// ---- qk: 2 queries per block; float4 keysT loads ----
__global__ __launch_bounds__(128)
void qk_kernel(const float* __restrict__ pooled, const int* __restrict__ idx,
               const float* __restrict__ q_w, const float* __restrict__ q_b,
               const float* __restrict__ keysT, float* __restrict__ out, int B, int N)
{
    const int n0 = blockIdx.x * 2, t = threadIdx.x;
    const int n1 = n0 + 1;
    const bool has1 = (n1 < N);
    __shared__ float p0[128], p1[128];
    __shared__ float q0[64], q1[64];
    const int bi0 = idx[n0];
    const int bi1 = has1 ? idx[n1] : bi0;
    p0[t] = pooled[(size_t)bi0 * 128 + t];
    p1[t] = pooled[(size_t)bi1 * 128 + t];
    __syncthreads();
    if (t < 64) {
        float s = q_b[t];
#pragma unroll
        for (int i = 0; i < 128; ++i) s = fmaf(p0[i], q_w[i * 64 + t], s);
        q0[t] = s;
    } else {
        const int tt = t - 64;
        float s = q_b[tt];
#pragma unroll
        for (int i = 0; i < 128; ++i) s = fmaf(p1[i], q_w[i * 64 + tt], s);
        q1[tt] = s;
    }
    __syncthreads();
    for (int m0 = t * 4; m0 < B; m0 += 512) {
        f32x4 a0 = {0.f, 0.f, 0.f, 0.f}, a1 = {0.f, 0.f, 0.f, 0.f};
#pragma unroll 8
        for (int i = 0; i < 64; ++i) {
            const float4 kv = *(const float4*)&keysT[(size_t)i * B + m0];
            const float qa = q0[i], qb = q1[i];
            a0[0] = fmaf(qa, kv.x, a0[0]); a0[1] = fmaf(qa, kv.y, a0[1]);
            a0[2] = fmaf(qa, kv.z, a0[2]); a0[3] = fmaf(qa, kv.w, a0[3]);
            a1[0] = fmaf(qb, kv.x, a1[0]); a1[1] = fmaf(qb, kv.y, a1[1]);
            a1[2] = fmaf(qb, kv.z, a1[2]); a1[3] = fmaf(qb, kv.w, a1[3]);
        }
        *(f32x4*)&out[(size_t)n0 * B + m0] = a0;
        if (has1) *(f32x4*)&out[(size_t)n1 * B + m0] = a1;
    }
}

// ============================ LAUNCH ============================

extern "C" void kernel_launch(void* const* d_in, const int* in_sizes, int n_in,
                              void* d_out, int out_size, void* d_ws, size_t ws_size,
                              hipStream_t stream)
{
    const float* reads      = (const float*)d_in[0];
    const int*   idx        = (const int*)d_in[1];
    const float* exp_w      = (const float*)d_in[2];
    const float* exp_b      = (const float*)d_in[3];
    const float* in_proj_w  = (const float*)d_in[4];
    const float* conv_w     = (const float*)d_in[5];
    const float* conv_b     = (const float*)d_in[6];
    const float* x_proj_w   = (const float*)d_in[7];
    const float* dt_w       = (const float*)d_in[8];
    const float* dt_b       = (const float*)d_in[9];
    const float* A_log      = (const float*)d_in[10];
    const float* D_skip     = (const float*)d_in[11];
    const float* out_proj_w = (const float*)d_in[12];
    const float* q_w        = (const float*)d_in[13];
    const float* q_b        = (const float*)d_in[14];
    const float* k_w        = (const float*)d_in[15];
    const float* k_b        = (const float*)d_in[16];

    const int B = in_sizes[0] / (L_SEQ * 4);
    const int N = in_sizes[1];

    char* wsb = (char*)d_ws;
    size_t off = 0;
    auto alloc = [&](size_t bytes) {
        size_t o = off;
        off = (off + bytes + 255) & ~(size_t)255;
        return o;
    };

    float*     pooled = (float*)(wsb + alloc((size_t)B * 128 * 4));
    float*     keysT  = (float*)(wsb + alloc((size_t)B * 64 * 4));
    _Float16*  WT     = (_Float16*)(wsb + alloc(160 * 128 * 2));
    _Float16*  W2     = (_Float16*)(wsb + alloc(256 * 32 * 2));
    float*     bias2  = (float*)(wsb + alloc(128 * 4));
    int*       sflag  = (int*)(wsb + alloc(256));

    const size_t pairs = (size_t)B * NSEG * 8 * 128;
    f16x2* Qg = (f16x2*)(wsb + alloc(pairs * 4));
    f16x2* Pg = (f16x2*)(wsb + alloc(pairs * 4));
    f16x2* Kg = (f16x2*)(wsb + alloc(pairs * 4));
    float* GS = (float*)(wsb + alloc((size_t)B * NSEG * 128 * 4));
    float* CZ = (float*)(wsb + alloc((size_t)B * 16 * 128 * 4));
    float* SL = (float*)(wsb + alloc((size_t)B * 128 * 4));

    k_prep<<<7, 256, 0, stream>>>(exp_w, exp_b, in_proj_w, x_proj_w, dt_w,
                                  conv_w, conv_b, A_log, WT, W2, bias2, sflag);
    mamba_seg<<<B * NSEG, 256, 0, stream>>>(reads, WT, W2, bias2, dt_b,
                                            A_log, D_skip, sflag, Qg, Pg, Kg,
                                            GS, CZ, SL, B);
    stitch<NSEG><<<B, 128, 0, stream>>>(Qg, Pg, Kg, GS, CZ, SL, out_proj_w, k_w, k_b,
                                        pooled, keysT, B);
    qk_kernel<<<(N + 1) / 2, 128, 0, stream>>>(pooled, idx, q_w, q_b, keysT,
                                               (float*)d_out, B, N);
}

// Round 15
// 127.345 us; speedup vs baseline: 2.4511x; 1.0252x over previous
//
#include <hip/hip_runtime.h>
#include <math.h>

#define L_SEQ 256
#define TILE 16
#define NSEG 16

typedef __attribute__((ext_vector_type(2))) float f32x2;
typedef __attribute__((ext_vector_type(4))) float f32x4;
typedef __attribute__((ext_vector_type(8))) _Float16 f16x8;
typedef __attribute__((ext_vector_type(4))) _Float16 f16x4;
typedef __attribute__((ext_vector_type(2))) _Float16 f16x2;

__device__ __forceinline__ f32x2 fma2(f32x2 a, f32x2 b, f32x2 c) {
    return __builtin_elementwise_fma(a, b, c);
}
__device__ __forceinline__ f32x2 splat2(float x) { f32x2 v = {x, x}; return v; }
__device__ __forceinline__ float rcp_f(float x) {
#if __has_builtin(__builtin_amdgcn_rcpf)
    return __builtin_amdgcn_rcpf(x);
#else
    return 1.f / x;
#endif
}
__device__ __forceinline__ float silu_f(float x) { return x * rcp_f(1.f + __expf(-x)); }

// ---- prep (one launch, 7 blocks):
//  blocks 0..4: WT[160][128] f16 = [x_proj[:,:4]@dt_w | x_proj[:,4:36]]^T
//  block 5:     W2[256][32] f16 (conv+expansion+in_proj folded) + bias2
//  block 6:     sflag = all channels have A[n] == -(n+1)
__global__ __launch_bounds__(256)
void k_prep(const float* __restrict__ exp_w, const float* __restrict__ exp_b,
            const float* __restrict__ in_proj_w, const float* __restrict__ x_proj_w,
            const float* __restrict__ dt_w,
            const float* __restrict__ conv_w, const float* __restrict__ conv_b,
            const float* __restrict__ A_log,
            _Float16* __restrict__ WT, _Float16* __restrict__ W2,
            float* __restrict__ bias2, int* __restrict__ sflag)
{
    const int t = threadIdx.x, blk = blockIdx.x;
    if (blk < 5) {
        const int base = blk * 4096;
        for (int i = base + t; i < base + 4096; i += 256) {
            const int row = i >> 7, k = i & 127;
            float v;
            if (row < 128) {
                v = x_proj_w[k * 36 + 0] * dt_w[row]
                  + x_proj_w[k * 36 + 1] * dt_w[128 + row]
                  + x_proj_w[k * 36 + 2] * dt_w[256 + row]
                  + x_proj_w[k * 36 + 3] * dt_w[384 + row];
            } else {
                v = x_proj_w[k * 36 + 4 + (row - 128)];
            }
            WT[i] = (_Float16)v;
        }
    } else if (blk == 5) {
        // thread t<128 -> xc channel d=t ; t>=128 -> z channel d=t-128
        const int d = t & 127;
        const int col = (t < 128) ? d : (128 + d);
        float w0 = 0, w1 = 0, w2 = 0, w3 = 0, bb = 0;
        for (int k = 0; k < 64; ++k) {
            float w = in_proj_w[k * 256 + col];
            w0 = fmaf(exp_w[k], w, w0);
            w1 = fmaf(exp_w[64 + k], w, w1);
            w2 = fmaf(exp_w[128 + k], w, w2);
            w3 = fmaf(exp_w[192 + k], w, w3);
            bb = fmaf(exp_b[k], w, bb);
        }
        const float wx[4] = {w0, w1, w2, w3};
        if (t < 128) {
            for (int j = 0; j < 32; ++j) {
                float v = 0.f;
                if (j < 16)      v = conv_w[d * 4 + (j >> 2)] * wx[j & 3];
                else if (j < 20) v = conv_w[d * 4 + (j - 16)] * bb;
                W2[d * 32 + j] = (_Float16)v;
            }
            bias2[d] = conv_b[d];
        } else {
            for (int j = 0; j < 32; ++j) {
                float v = 0.f;
                if (j >= 12 && j < 16) v = wx[j - 12];
                else if (j == 19)      v = bb;
                W2[(128 + d) * 32 + j] = (_Float16)v;
            }
        }
    } else {
        __shared__ int ok;
        if (t == 0) ok = 1;
        __syncthreads();
        bool good = true;
        for (int i = t; i < 2048; i += 256) {
            float a = -__expf(A_log[i]);
            good = good && (fabsf(a + (float)((i & 15) + 1)) < 1e-3f);
        }
        if (!good) atomicAnd(&ok, 0);
        __syncthreads();
        if (t == 0) sflag[0] = ok;
    }
}

// ---- fused Mamba: grid = B*16 blocks x 256 threads, one 16-step segment each ----
// DZR[l][ch] = {delta, r=exp(-delta), zs, xc} packed f16x4: scan does 1 ds_read_b64,
// no per-step exp2, no per-step cross-lane shuffle.
__global__ __launch_bounds__(256, 6)
void mamba_seg(const float* __restrict__ reads,
               const _Float16* __restrict__ WT, const _Float16* __restrict__ W2,
               const float* __restrict__ bias2, const float* __restrict__ dt_b,
               const float* __restrict__ A_log, const float* __restrict__ D_skip,
               const int* __restrict__ sflag,
               f16x2* __restrict__ Qg, f16x2* __restrict__ Pg, f16x2* __restrict__ Kg,
               float* __restrict__ GS, float* __restrict__ CZ, float* __restrict__ SL,
               int Bn)
{
    const int bx = blockIdx.x;
    const int b = bx >> 4, sidx = bx & 15;
    const int l_off = sidx * TILE;
    const int t = threadIdx.x;
    const int dd = t >> 1, g = t & 1;          // phase E: channel, state-half

    __shared__ __align__(16) _Float16 F[TILE * 40];        // features, K-padded
    __shared__ __align__(16) _Float16 XC[TILE * 136];      // conv out (silu), MFMA A
    __shared__ __align__(8)  _Float16 DZR[TILE * 128 * 4]; // {de, r, zs, xc}
    __shared__ __align__(16) float    BC[TILE * 32];       // B(16)|C(16) per step

    const float dskip = D_skip[dd];
    const bool structured = (sflag[0] != 0);

    // ---- build F[16][40]: taps(16) | bias indicators(4) | pad ----
    for (int i = t; i < TILE * 40; i += 256) {
        const int l = i / 40, j = i - l * 40;
        _Float16 v = (_Float16)0.f;
        if (j < 16) {
            const int row = l_off + l - 3 + (j >> 2);
            if (row >= 0) v = (_Float16)reads[((size_t)b * L_SEQ + row) * 4 + (j & 3)];
        } else if (j < 20) {
            v = (l_off + l - 3 + (j - 16) >= 0) ? (_Float16)1.f : (_Float16)0.f;
        }
        F[i] = v;
    }
    __syncthreads();

    const int lane = t & 63, wv = t >> 6;
    const int fcol = lane & 15, kq = lane >> 4, rbase = kq * 4;

    // ---- phase A: MFMA [16 x 256] = F[16x32] @ W2^T ; silu -> XC | DZR.zs/.xc ----
#pragma unroll
    for (int i = 0; i < 4; ++i) {
        const int n = wv + 4 * i;              // 16 tasks over 4 waves
        f16x8 af = *(const f16x8*)&F[fcol * 40 + kq * 8];
        f16x8 bf = *(const f16x8*)&W2[(n * 16 + fcol) * 32 + kq * 8];
        f32x4 acc = {0.f, 0.f, 0.f, 0.f};
        acc = __builtin_amdgcn_mfma_f32_16x16x32_f16(af, bf, acc, 0, 0, 0);
        if (n < 8) {
            const int ch = n * 16 + fcol;
            const float bv = bias2[ch];
#pragma unroll
            for (int r = 0; r < 4; ++r) {
                const float hx = silu_f(acc[r] + bv);
                XC[(rbase + r) * 136 + ch] = (_Float16)hx;
                DZR[((rbase + r) * 128 + ch) * 4 + 3] = (_Float16)hx;
            }
        } else {
            const int ch = (n - 8) * 16 + fcol;
#pragma unroll
            for (int r = 0; r < 4; ++r)
                DZR[((rbase + r) * 128 + ch) * 4 + 2] = (_Float16)silu_f(acc[r]);
        }
    }
    __syncthreads();

    // ---- phase C: MFMA [16 x 160] = XC @ WT^T -> DZR.de/.r (softplus+sigmoid) | BC ----
#pragma unroll
    for (int i = 0; i < 3; ++i) {
        const int n = wv + 4 * i;              // 10 tasks over 4 waves
        if (n < 10) {
            f32x4 acc = {0.f, 0.f, 0.f, 0.f};
#pragma unroll
            for (int ks = 0; ks < 4; ++ks) {
                const int ko = ks * 32 + kq * 8;
                f16x8 xa = *(const f16x8*)&XC[fcol * 136 + ko];
                f16x8 bf = *(const f16x8*)&WT[(n * 16 + fcol) * 128 + ko];
                acc = __builtin_amdgcn_mfma_f32_16x16x32_f16(xa, bf, acc, 0, 0, 0);
            }
            if (n < 8) {
                const int ch = n * 16 + fcol;
                const float db = dt_b[ch];
#pragma unroll
                for (int r = 0; r < 4; ++r) {
                    const float dtr = fminf(acc[r] + db, 80.f);
                    const float ex = __expf(dtr);            // e^dtr (finite: dtr<=80)
                    const float opx = 1.f + ex;
                    const float de = __logf(opx);            // softplus(dtr)
                    const float rr = rcp_f(opx);             // exp(-de)
                    const int o = ((rbase + r) * 128 + ch) * 4;
                    DZR[o]     = (_Float16)de;
                    DZR[o + 1] = (_Float16)rr;
                }
            } else {
                const int jb = (n - 8) * 16 + fcol;
#pragma unroll
                for (int r = 0; r < 4; ++r)
                    BC[(rbase + r) * 32 + jb] = acc[r];
            }
        }
    }
    __syncthreads();

    // ---- phase E: 16-step serial scan; 2 lanes/channel, shuffle-free steps ----
    f32x2 h2[4], P2[4], K2[4];
#pragma unroll
    for (int k = 0; k < 4; ++k) { h2[k] = splat2(0.f); P2[k] = splat2(1.f); K2[k] = splat2(0.f); }
    f32x2 gs2 = splat2(0.f);
    float xz = 0.f;
    {
        auto scan_loop = [&](bool needpk) {
            for (int l = 0; l < TILE; ++l) {
                const f16x4 dz = *(const f16x4*)&DZR[(l * 128 + dd) * 4];
                const float de = (float)dz[0];
                const float rr = (float)dz[1];
                const float zs = (float)dz[2];
                const float xc = (float)dz[3];
                const float du = de * xc;
                f32x2 E2[4];
                if (structured) {              // states 8g+1..8g+8: powers of r (no exp2)
                    const float r2 = rr * rr;
                    const float r4 = r2 * r2;
                    const float t1 = g ? (r4 * r4 * rr) : rr;   // r^(8g+1)
                    E2[0] = (f32x2){t1, t1 * rr};
                    const f32x2 r2s = splat2(r2);
                    E2[1] = E2[0] * r2s;
                    E2[2] = E2[1] * r2s;
                    E2[3] = E2[2] * r2s;
                } else {                       // cold generic path
#pragma unroll
                    for (int k = 0; k < 4; ++k) {
                        float e0 = exp2f(de * (-__expf(A_log[dd * 16 + g * 8 + 2 * k])) * 1.44269504f);
                        float e1 = exp2f(de * (-__expf(A_log[dd * 16 + g * 8 + 2 * k + 1])) * 1.44269504f);
                        E2[k] = (f32x2){e0, e1};
                    }
                }
                const float4 Bq0 = *(const float4*)&BC[l * 32 + g * 8];
                const float4 Bq1 = *(const float4*)&BC[l * 32 + g * 8 + 4];
                const float4 Cq0 = *(const float4*)&BC[l * 32 + 16 + g * 8];
                const float4 Cq1 = *(const float4*)&BC[l * 32 + 16 + g * 8 + 4];
                const f32x2 B2[4] = {{Bq0.x, Bq0.y}, {Bq0.z, Bq0.w}, {Bq1.x, Bq1.y}, {Bq1.z, Bq1.w}};
                const f32x2 C2[4] = {{Cq0.x, Cq0.y}, {Cq0.z, Cq0.w}, {Cq1.x, Cq1.y}, {Cq1.z, Cq1.w}};
                const f32x2 dus = splat2(du), zss = splat2(zs);
                f32x2 yp2 = splat2(0.f);
#pragma unroll
                for (int k = 0; k < 4; ++k) {
                    h2[k] = fma2(E2[k], h2[k], dus * B2[k]);
                    yp2 = fma2(h2[k], C2[k], yp2);
                    if (needpk) {
                        P2[k] = P2[k] * E2[k];
                        K2[k] = fma2(zss, C2[k] * P2[k], K2[k]);
                    }
                }
                gs2 = fma2(yp2, zss, gs2);     // per-lane partial; combined once at end
                xz = fmaf(xc, zs, xz);         // skip-term partial (lane-uniform)
            }
        };
        if (sidx == 0) scan_loop(false);
        else           scan_loop(true);
    }

    // ---- segment summary writeout (LDS still holds the tile) ----
    {
        const size_t sb = (size_t)sidx * Bn + b;
#pragma unroll
        for (int k = 0; k < 4; ++k) {
            const size_t o = (sb * 8 + g * 4 + k) * 128 + dd;   // pair p = g*4+k
            Qg[o] = (f16x2){(_Float16)h2[k].x, (_Float16)h2[k].y};
            if (sidx != 0) {
                Pg[o] = (f16x2){(_Float16)P2[k].x, (_Float16)P2[k].y};
                Kg[o] = (f16x2){(_Float16)K2[k].x, (_Float16)K2[k].y};
            }
        }
        float gsp = gs2.x + gs2.y;
        gsp += __shfl_xor(gsp, 1);             // combine lane partials once
        const float gsum = fmaf(dskip, xz, gsp);
        if (g == 0) GS[sb * 128 + dd] = gsum;
        if (sidx == NSEG - 1) {
            const f16x4 lastv = *(const f16x4*)&DZR[((TILE - 1) * 128 + dd) * 4];
            const float zs_last = (float)lastv[2];
            const float xc_last = (float)lastv[3];
#pragma unroll
            for (int k = 0; k < 8; ++k)
                CZ[((size_t)b * 16 + g * 8 + k) * 128 + dd] =
                    zs_last * BC[(TILE - 1) * 32 + 16 + g * 8 + k];
            if (g == 0) SL[(size_t)b * 128 + dd] = zs_last * xc_last * dskip;
        }
    }
}

// ---- stitch: 256 threads; (channel, state-half) split mirrors the scan ----
template<int NS>
__global__ __launch_bounds__(256)
void stitch(const f16x2* __restrict__ Qg, const f16x2* __restrict__ Pg,
            const f16x2* __restrict__ Kg, const float* __restrict__ GS,
            const float* __restrict__ CZ, const float* __restrict__ SL,
            const float* __restrict__ out_proj_w,
            const float* __restrict__ k_w, const float* __restrict__ k_b,
            float* __restrict__ pooled, float* __restrict__ keysT, int Bn)
{
    const int b = blockIdx.x, t = threadIdx.x;
    const int d = t >> 1, g = t & 1;
    __shared__ float gb[256];
    __shared__ float pl[128];

    float h[8];                                    // states 8g..8g+7 (pairs g*4..g*4+3)
    float gsum = (g == 0) ? GS[(size_t)b * 128 + d] : 0.f;
#pragma unroll
    for (int k = 0; k < 4; ++k) {
        f16x2 q = Qg[((size_t)b * 8 + g * 4 + k) * 128 + d];
        h[2 * k] = (float)q[0]; h[2 * k + 1] = (float)q[1];
    }
#pragma unroll
    for (int s = 1; s < NS; ++s) {
        const size_t sb = (size_t)s * Bn + b;
        if (g == 0) gsum += GS[sb * 128 + d];
        float corr = 0.f;
#pragma unroll
        for (int k = 0; k < 4; ++k) {
            const size_t o = (sb * 8 + g * 4 + k) * 128 + d;
            f16x2 qv = Qg[o], pv = Pg[o], kv = Kg[o];
            corr = fmaf((float)kv[0], h[2 * k], corr);
            corr = fmaf((float)kv[1], h[2 * k + 1], corr);
            h[2 * k]     = fmaf((float)pv[0], h[2 * k],     (float)qv[0]);
            h[2 * k + 1] = fmaf((float)pv[1], h[2 * k + 1], (float)qv[1]);
        }
        gsum += corr;
    }
    float glast = (g == 0) ? SL[(size_t)b * 128 + d] : 0.f;
#pragma unroll
    for (int k = 0; k < 8; ++k)
        glast = fmaf(CZ[((size_t)b * 16 + g * 8 + k) * 128 + d], h[k], glast);

    gsum += __shfl_xor(gsum, 1);
    glast += __shfl_xor(glast, 1);
    if (g == 0) { gb[d] = gsum * (1.f / (float)L_SEQ); gb[128 + d] = glast; }
    __syncthreads();

    // out_proj: 128 outputs x 2 threads each (split the 128-dot)
    {
        const int oi = t >> 1;                 // 0..127
        const int half = oi >> 6, oc = oi & 63;
        const float* gbp = &gb[half * 128];
        float s = 0.f;
#pragma unroll 16
        for (int i = g * 64; i < g * 64 + 64; ++i)
            s = fmaf(gbp[i], out_proj_w[i * 64 + oc], s);
        s += __shfl_xor(s, 1);
        if (g == 0) { pooled[(size_t)b * 128 + oi] = s; pl[oi] = s; }
    }
    __syncthreads();

    // keys: 64 outputs x 2 threads each
    if (t < 128) {
        const int oc = t >> 1;
        float s = (g == 0) ? k_b[oc] : 0.f;
#pragma unroll 16
        for (int i = g * 64; i < g * 64 + 64; ++i)
            s = fmaf(pl[i], k_w[i * 64 + oc], s);
        s += __shfl_xor(s, 1);
        if (g == 0) keysT[(size_t)oc * Bn + b] = s;
    }
}

// ---- qk: 2 queries per block; float4 keysT loads ----
__global__ __launch_bounds__(128)
void qk_kernel(const float* __restrict__ pooled, const int* __restrict__ idx,
               const float* __restrict__ q_w, const float* __restrict__ q_b,
               const float* __restrict__ keysT, float* __restrict__ out, int B, int N)
{
    const int n0 = blockIdx.x * 2, t = threadIdx.x;
    const int n1 = n0 + 1;
    const bool has1 = (n1 < N);
    __shared__ float p0[128], p1[128];
    __shared__ float q0[64], q1[64];
    const int bi0 = idx[n0];
    const int bi1 = has1 ? idx[n1] : bi0;
    p0[t] = pooled[(size_t)bi0 * 128 + t];
    p1[t] = pooled[(size_t)bi1 * 128 + t];
    __syncthreads();
    if (t < 64) {
        float s = q_b[t];
#pragma unroll
        for (int i = 0; i < 128; ++i) s = fmaf(p0[i], q_w[i * 64 + t], s);
        q0[t] = s;
    } else {
        const int tt = t - 64;
        float s = q_b[tt];
#pragma unroll
        for (int i = 0; i < 128; ++i) s = fmaf(p1[i], q_w[i * 64 + tt], s);
        q1[tt] = s;
    }
    __syncthreads();
    for (int m0 = t * 4; m0 < B; m0 += 512) {
        f32x4 a0 = {0.f, 0.f, 0.f, 0.f}, a1 = {0.f, 0.f, 0.f, 0.f};
#pragma unroll 8
        for (int i = 0; i < 64; ++i) {
            const float4 kv = *(const float4*)&keysT[(size_t)i * B + m0];
            const float qa = q0[i], qb = q1[i];
            a0[0] = fmaf(qa, kv.x, a0[0]); a0[1] = fmaf(qa, kv.y, a0[1]);
            a0[2] = fmaf(qa, kv.z, a0[2]); a0[3] = fmaf(qa, kv.w, a0[3]);
            a1[0] = fmaf(qb, kv.x, a1[0]); a1[1] = fmaf(qb, kv.y, a1[1]);
            a1[2] = fmaf(qb, kv.z, a1[2]); a1[3] = fmaf(qb, kv.w, a1[3]);
        }
        *(f32x4*)&out[(size_t)n0 * B + m0] = a0;
        if (has1) *(f32x4*)&out[(size_t)n1 * B + m0] = a1;
    }
}

// ============================ LAUNCH ============================

extern "C" void kernel_launch(void* const* d_in, const int* in_sizes, int n_in,
                              void* d_out, int out_size, void* d_ws, size_t ws_size,
                              hipStream_t stream)
{
    const float* reads      = (const float*)d_in[0];
    const int*   idx        = (const int*)d_in[1];
    const float* exp_w      = (const float*)d_in[2];
    const float* exp_b      = (const float*)d_in[3];
    const float* in_proj_w  = (const float*)d_in[4];
    const float* conv_w     = (const float*)d_in[5];
    const float* conv_b     = (const float*)d_in[6];
    const float* x_proj_w   = (const float*)d_in[7];
    const float* dt_w       = (const float*)d_in[8];
    const float* dt_b       = (const float*)d_in[9];
    const float* A_log      = (const float*)d_in[10];
    const float* D_skip     = (const float*)d_in[11];
    const float* out_proj_w = (const float*)d_in[12];
    const float* q_w        = (const float*)d_in[13];
    const float* q_b        = (const float*)d_in[14];
    const float* k_w        = (const float*)d_in[15];
    const float* k_b        = (const float*)d_in[16];

    const int B = in_sizes[0] / (L_SEQ * 4);
    const int N = in_sizes[1];

    char* wsb = (char*)d_ws;
    size_t off = 0;
    auto alloc = [&](size_t bytes) {
        size_t o = off;
        off = (off + bytes + 255) & ~(size_t)255;
        return o;
    };

    float*     pooled = (float*)(wsb + alloc((size_t)B * 128 * 4));
    float*     keysT  = (float*)(wsb + alloc((size_t)B * 64 * 4));
    _Float16*  WT     = (_Float16*)(wsb + alloc(160 * 128 * 2));
    _Float16*  W2     = (_Float16*)(wsb + alloc(256 * 32 * 2));
    float*     bias2  = (float*)(wsb + alloc(128 * 4));
    int*       sflag  = (int*)(wsb + alloc(256));

    const size_t pairs = (size_t)B * NSEG * 8 * 128;
    f16x2* Qg = (f16x2*)(wsb + alloc(pairs * 4));
    f16x2* Pg = (f16x2*)(wsb + alloc(pairs * 4));
    f16x2* Kg = (f16x2*)(wsb + alloc(pairs * 4));
    float* GS = (float*)(wsb + alloc((size_t)B * NSEG * 128 * 4));
    float* CZ = (float*)(wsb + alloc((size_t)B * 16 * 128 * 4));
    float* SL = (float*)(wsb + alloc((size_t)B * 128 * 4));

    k_prep<<<7, 256, 0, stream>>>(exp_w, exp_b, in_proj_w, x_proj_w, dt_w,
                                  conv_w, conv_b, A_log, WT, W2, bias2, sflag);
    mamba_seg<<<B * NSEG, 256, 0, stream>>>(reads, WT, W2, bias2, dt_b,
                                            A_log, D_skip, sflag, Qg, Pg, Kg,
                                            GS, CZ, SL, B);
    stitch<NSEG><<<B, 256, 0, stream>>>(Qg, Pg, Kg, GS, CZ, SL, out_proj_w, k_w, k_b,
                                        pooled, keysT, B);
    qk_kernel<<<(N + 1) / 2, 128, 0, stream>>>(pooled, idx, q_w, q_b, keysT,
                                               (float*)d_out, B, N);
}

// Round 16
// 125.924 us; speedup vs baseline: 2.4788x; 1.0113x over previous
//
#include <hip/hip_runtime.h>
#include <math.h>

#define L_SEQ 256
#define TILE 16
#define NSEG 16

typedef __attribute__((ext_vector_type(2))) float f32x2;
typedef __attribute__((ext_vector_type(4))) float f32x4;
typedef __attribute__((ext_vector_type(8))) _Float16 f16x8;
typedef __attribute__((ext_vector_type(4))) _Float16 f16x4;
typedef __attribute__((ext_vector_type(2))) _Float16 f16x2;

__device__ __forceinline__ f32x2 fma2(f32x2 a, f32x2 b, f32x2 c) {
    return __builtin_elementwise_fma(a, b, c);
}
__device__ __forceinline__ f32x2 splat2(float x) { f32x2 v = {x, x}; return v; }
__device__ __forceinline__ float rcp_f(float x) {
#if __has_builtin(__builtin_amdgcn_rcpf)
    return __builtin_amdgcn_rcpf(x);
#else
    return 1.f / x;
#endif
}
__device__ __forceinline__ float silu_f(float x) { return x * rcp_f(1.f + __expf(-x)); }

// ---- prep (one launch, 7 blocks):
//  blocks 0..4: WT[160][128] f16 = [x_proj[:,:4]@dt_w | x_proj[:,4:36]]^T
//  block 5:     W2[256][32] f16 (conv+expansion+in_proj folded) + bias2
//  block 6:     sflag = all channels have A[n] == -(n+1)
__global__ __launch_bounds__(256)
void k_prep(const float* __restrict__ exp_w, const float* __restrict__ exp_b,
            const float* __restrict__ in_proj_w, const float* __restrict__ x_proj_w,
            const float* __restrict__ dt_w,
            const float* __restrict__ conv_w, const float* __restrict__ conv_b,
            const float* __restrict__ A_log,
            _Float16* __restrict__ WT, _Float16* __restrict__ W2,
            float* __restrict__ bias2, int* __restrict__ sflag)
{
    const int t = threadIdx.x, blk = blockIdx.x;
    if (blk < 5) {
        const int base = blk * 4096;
        for (int i = base + t; i < base + 4096; i += 256) {
            const int row = i >> 7, k = i & 127;
            float v;
            if (row < 128) {
                v = x_proj_w[k * 36 + 0] * dt_w[row]
                  + x_proj_w[k * 36 + 1] * dt_w[128 + row]
                  + x_proj_w[k * 36 + 2] * dt_w[256 + row]
                  + x_proj_w[k * 36 + 3] * dt_w[384 + row];
            } else {
                v = x_proj_w[k * 36 + 4 + (row - 128)];
            }
            WT[i] = (_Float16)v;
        }
    } else if (blk == 5) {
        // thread t<128 -> xc channel d=t ; t>=128 -> z channel d=t-128
        const int d = t & 127;
        const int col = (t < 128) ? d : (128 + d);
        float w0 = 0, w1 = 0, w2 = 0, w3 = 0, bb = 0;
        for (int k = 0; k < 64; ++k) {
            float w = in_proj_w[k * 256 + col];
            w0 = fmaf(exp_w[k], w, w0);
            w1 = fmaf(exp_w[64 + k], w, w1);
            w2 = fmaf(exp_w[128 + k], w, w2);
            w3 = fmaf(exp_w[192 + k], w, w3);
            bb = fmaf(exp_b[k], w, bb);
        }
        const float wx[4] = {w0, w1, w2, w3};
        if (t < 128) {
            for (int j = 0; j < 32; ++j) {
                float v = 0.f;
                if (j < 16)      v = conv_w[d * 4 + (j >> 2)] * wx[j & 3];
                else if (j < 20) v = conv_w[d * 4 + (j - 16)] * bb;
                W2[d * 32 + j] = (_Float16)v;
            }
            bias2[d] = conv_b[d];
        } else {
            for (int j = 0; j < 32; ++j) {
                float v = 0.f;
                if (j >= 12 && j < 16) v = wx[j - 12];
                else if (j == 19)      v = bb;
                W2[(128 + d) * 32 + j] = (_Float16)v;
            }
        }
    } else {
        __shared__ int ok;
        if (t == 0) ok = 1;
        __syncthreads();
        bool good = true;
        for (int i = t; i < 2048; i += 256) {
            float a = -__expf(A_log[i]);
            good = good && (fabsf(a + (float)((i & 15) + 1)) < 1e-3f);
        }
        if (!good) atomicAnd(&ok, 0);
        __syncthreads();
        if (t == 0) sflag[0] = ok;
    }
}

// ---- fused Mamba: grid = B*16 blocks x 256 threads, one 16-step segment each ----
// LDS diet (20,224 B -> 8 blocks/CU) + conflict-free padded strides (130/132).
__global__ __launch_bounds__(256, 8)
void mamba_seg(const float* __restrict__ reads,
               const _Float16* __restrict__ WT, const _Float16* __restrict__ W2,
               const float* __restrict__ bias2, const float* __restrict__ dt_b,
               const float* __restrict__ A_log, const float* __restrict__ D_skip,
               const int* __restrict__ sflag,
               f16x2* __restrict__ Qg, f16x2* __restrict__ Pg, f16x2* __restrict__ Kg,
               float* __restrict__ GS, float* __restrict__ CZ, float* __restrict__ SL,
               int Bn)
{
    const int bx = blockIdx.x;
    const int b = bx >> 4, sidx = bx & 15;
    const int l_off = sidx * TILE;
    const int t = threadIdx.x;
    const int dd = t >> 1, g = t & 1;          // phase E: channel, state-half

    __shared__ __align__(16) _Float16 F[TILE * 40];    // features, K-padded
    __shared__ __align__(16) _Float16 XC[TILE * 136];  // conv out (silu), MFMA A
    __shared__ __align__(8)  f16x2    DR[TILE * 130];  // {delta, r}, padded stride
    __shared__ _Float16               ZS[TILE * 132];  // silu(z), padded stride
    __shared__ __align__(16) float    BC[TILE * 32];   // B(16)|C(16) per step

    const float dskip = D_skip[dd];
    const bool structured = (sflag[0] != 0);

    // ---- build F[16][40]: taps(16) | bias indicators(4) | pad ----
    for (int i = t; i < TILE * 40; i += 256) {
        const int l = i / 40, j = i - l * 40;
        _Float16 v = (_Float16)0.f;
        if (j < 16) {
            const int row = l_off + l - 3 + (j >> 2);
            if (row >= 0) v = (_Float16)reads[((size_t)b * L_SEQ + row) * 4 + (j & 3)];
        } else if (j < 20) {
            v = (l_off + l - 3 + (j - 16) >= 0) ? (_Float16)1.f : (_Float16)0.f;
        }
        F[i] = v;
    }
    __syncthreads();

    const int lane = t & 63, wv = t >> 6;
    const int fcol = lane & 15, kq = lane >> 4, rbase = kq * 4;

    // ---- phase A: MFMA [16 x 256] = F[16x32] @ W2^T ; silu -> XC | ZS ----
#pragma unroll
    for (int i = 0; i < 4; ++i) {
        const int n = wv + 4 * i;              // 16 tasks over 4 waves
        f16x8 af = *(const f16x8*)&F[fcol * 40 + kq * 8];
        f16x8 bf = *(const f16x8*)&W2[(n * 16 + fcol) * 32 + kq * 8];
        f32x4 acc = {0.f, 0.f, 0.f, 0.f};
        acc = __builtin_amdgcn_mfma_f32_16x16x32_f16(af, bf, acc, 0, 0, 0);
        if (n < 8) {
            const int ch = n * 16 + fcol;
            const float bv = bias2[ch];
#pragma unroll
            for (int r = 0; r < 4; ++r)
                XC[(rbase + r) * 136 + ch] = (_Float16)silu_f(acc[r] + bv);
        } else {
            const int ch = (n - 8) * 16 + fcol;
#pragma unroll
            for (int r = 0; r < 4; ++r)
                ZS[(rbase + r) * 132 + ch] = (_Float16)silu_f(acc[r]);
        }
    }
    __syncthreads();

    // ---- phase C: MFMA [16 x 160] = XC @ WT^T -> DR {softplus, sigmoid} | BC ----
#pragma unroll
    for (int i = 0; i < 3; ++i) {
        const int n = wv + 4 * i;              // 10 tasks over 4 waves
        if (n < 10) {
            f32x4 acc = {0.f, 0.f, 0.f, 0.f};
#pragma unroll
            for (int ks = 0; ks < 4; ++ks) {
                const int ko = ks * 32 + kq * 8;
                f16x8 xa = *(const f16x8*)&XC[fcol * 136 + ko];
                f16x8 bf = *(const f16x8*)&WT[(n * 16 + fcol) * 128 + ko];
                acc = __builtin_amdgcn_mfma_f32_16x16x32_f16(xa, bf, acc, 0, 0, 0);
            }
            if (n < 8) {
                const int ch = n * 16 + fcol;
                const float db = dt_b[ch];
#pragma unroll
                for (int r = 0; r < 4; ++r) {
                    const float dtr = fminf(acc[r] + db, 80.f);
                    const float ex = __expf(dtr);            // e^dtr (finite)
                    const float opx = 1.f + ex;
                    const float de = __logf(opx);            // softplus(dtr)
                    const float rr = rcp_f(opx);             // exp(-de)
                    DR[(rbase + r) * 130 + ch] = (f16x2){(_Float16)de, (_Float16)rr};
                }
            } else {
                const int jb = (n - 8) * 16 + fcol;
#pragma unroll
                for (int r = 0; r < 4; ++r)
                    BC[(rbase + r) * 32 + jb] = acc[r];
            }
        }
    }
    __syncthreads();

    // ---- phase E: 16-step serial scan; 2 lanes/channel, shuffle-free steps ----
    f32x2 h2[4], P2[4], K2[4];
#pragma unroll
    for (int k = 0; k < 4; ++k) { h2[k] = splat2(0.f); P2[k] = splat2(1.f); K2[k] = splat2(0.f); }
    f32x2 gs2 = splat2(0.f);
    float xz = 0.f;
    {
        auto scan_loop = [&](bool needpk) {
            for (int l = 0; l < TILE; ++l) {
                const f16x2 dz = DR[l * 130 + dd];
                const float de = (float)dz[0];
                const float rr = (float)dz[1];
                const float zs = (float)ZS[l * 132 + dd];
                const float xc = (float)XC[l * 136 + dd];
                const float du = de * xc;
                f32x2 E2[4];
                if (structured) {              // states 8g+1..8g+8: powers of r
                    const float r2 = rr * rr;
                    const float r4 = r2 * r2;
                    const float t1 = g ? (r4 * r4 * rr) : rr;   // r^(8g+1)
                    E2[0] = (f32x2){t1, t1 * rr};
                    const f32x2 r2s = splat2(r2);
                    E2[1] = E2[0] * r2s;
                    E2[2] = E2[1] * r2s;
                    E2[3] = E2[2] * r2s;
                } else {                       // cold generic path
#pragma unroll
                    for (int k = 0; k < 4; ++k) {
                        float e0 = exp2f(de * (-__expf(A_log[dd * 16 + g * 8 + 2 * k])) * 1.44269504f);
                        float e1 = exp2f(de * (-__expf(A_log[dd * 16 + g * 8 + 2 * k + 1])) * 1.44269504f);
                        E2[k] = (f32x2){e0, e1};
                    }
                }
                const float4 Bq0 = *(const float4*)&BC[l * 32 + g * 8];
                const float4 Bq1 = *(const float4*)&BC[l * 32 + g * 8 + 4];
                const float4 Cq0 = *(const float4*)&BC[l * 32 + 16 + g * 8];
                const float4 Cq1 = *(const float4*)&BC[l * 32 + 16 + g * 8 + 4];
                const f32x2 B2[4] = {{Bq0.x, Bq0.y}, {Bq0.z, Bq0.w}, {Bq1.x, Bq1.y}, {Bq1.z, Bq1.w}};
                const f32x2 C2[4] = {{Cq0.x, Cq0.y}, {Cq0.z, Cq0.w}, {Cq1.x, Cq1.y}, {Cq1.z, Cq1.w}};
                const f32x2 dus = splat2(du), zss = splat2(zs);
                f32x2 yp2 = splat2(0.f);
#pragma unroll
                for (int k = 0; k < 4; ++k) {
                    h2[k] = fma2(E2[k], h2[k], dus * B2[k]);
                    yp2 = fma2(h2[k], C2[k], yp2);
                    if (needpk) {
                        P2[k] = P2[k] * E2[k];
                        K2[k] = fma2(zss, C2[k] * P2[k], K2[k]);
                    }
                }
                gs2 = fma2(yp2, zss, gs2);     // per-lane partial
                xz = fmaf(xc, zs, xz);         // skip-term partial
            }
        };
        if (sidx == 0) scan_loop(false);
        else           scan_loop(true);
    }

    // ---- segment summary writeout (LDS still holds the tile) ----
    {
        const size_t sb = (size_t)sidx * Bn + b;
#pragma unroll
        for (int k = 0; k < 4; ++k) {
            const size_t o = (sb * 8 + g * 4 + k) * 128 + dd;   // pair p = g*4+k
            Qg[o] = (f16x2){(_Float16)h2[k].x, (_Float16)h2[k].y};
            if (sidx != 0) {
                Pg[o] = (f16x2){(_Float16)P2[k].x, (_Float16)P2[k].y};
                Kg[o] = (f16x2){(_Float16)K2[k].x, (_Float16)K2[k].y};
            }
        }
        float gsp = gs2.x + gs2.y;
        gsp += __shfl_xor(gsp, 1);             // combine lane partials once
        const float gsum = fmaf(dskip, xz, gsp);
        if (g == 0) GS[sb * 128 + dd] = gsum;
        if (sidx == NSEG - 1) {
            const float zs_last = (float)ZS[(TILE - 1) * 132 + dd];
            const float xc_last = (float)XC[(TILE - 1) * 136 + dd];
#pragma unroll
            for (int k = 0; k < 8; ++k)
                CZ[((size_t)b * 16 + g * 8 + k) * 128 + dd] =
                    zs_last * BC[(TILE - 1) * 32 + 16 + g * 8 + k];
            if (g == 0) SL[(size_t)b * 128 + dd] = zs_last * xc_last * dskip;
        }
    }
}

// ---- stitch: 256 threads; (channel, state-half) split mirrors the scan ----
template<int NS>
__global__ __launch_bounds__(256)
void stitch(const f16x2* __restrict__ Qg, const f16x2* __restrict__ Pg,
            const f16x2* __restrict__ Kg, const float* __restrict__ GS,
            const float* __restrict__ CZ, const float* __restrict__ SL,
            const float* __restrict__ out_proj_w,
            const float* __restrict__ k_w, const float* __restrict__ k_b,
            float* __restrict__ pooled, float* __restrict__ keysT, int Bn)
{
    const int b = blockIdx.x, t = threadIdx.x;
    const int d = t >> 1, g = t & 1;
    __shared__ float gb[256];
    __shared__ float pl[128];

    float h[8];                                    // states 8g..8g+7
    float gsum = (g == 0) ? GS[(size_t)b * 128 + d] : 0.f;
#pragma unroll
    for (int k = 0; k < 4; ++k) {
        f16x2 q = Qg[((size_t)b * 8 + g * 4 + k) * 128 + d];
        h[2 * k] = (float)q[0]; h[2 * k + 1] = (float)q[1];
    }
#pragma unroll
    for (int s = 1; s < NS; ++s) {
        const size_t sb = (size_t)s * Bn + b;
        if (g == 0) gsum += GS[sb * 128 + d];
        float corr = 0.f;
#pragma unroll
        for (int k = 0; k < 4; ++k) {
            const size_t o = (sb * 8 + g * 4 + k) * 128 + d;
            f16x2 qv = Qg[o], pv = Pg[o], kv = Kg[o];
            corr = fmaf((float)kv[0], h[2 * k], corr);
            corr = fmaf((float)kv[1], h[2 * k + 1], corr);
            h[2 * k]     = fmaf((float)pv[0], h[2 * k],     (float)qv[0]);
            h[2 * k + 1] = fmaf((float)pv[1], h[2 * k + 1], (float)qv[1]);
        }
        gsum += corr;
    }
    float glast = (g == 0) ? SL[(size_t)b * 128 + d] : 0.f;
#pragma unroll
    for (int k = 0; k < 8; ++k)
        glast = fmaf(CZ[((size_t)b * 16 + g * 8 + k) * 128 + d], h[k], glast);

    gsum += __shfl_xor(gsum, 1);
    glast += __shfl_xor(glast, 1);
    if (g == 0) { gb[d] = gsum * (1.f / (float)L_SEQ); gb[128 + d] = glast; }
    __syncthreads();

    // out_proj: 128 outputs x 2 threads each
    {
        const int oi = t >> 1;                 // 0..127
        const int half = oi >> 6, oc = oi & 63;
        const float* gbp = &gb[half * 128];
        float s = 0.f;
#pragma unroll 16
        for (int i = g * 64; i < g * 64 + 64; ++i)
            s = fmaf(gbp[i], out_proj_w[i * 64 + oc], s);
        s += __shfl_xor(s, 1);
        if (g == 0) { pooled[(size_t)b * 128 + oi] = s; pl[oi] = s; }
    }
    __syncthreads();

    // keys: 64 outputs x 2 threads each
    if (t < 128) {
        const int oc = t >> 1;
        float s = (g == 0) ? k_b[oc] : 0.f;
#pragma unroll 16
        for (int i = g * 64; i < g * 64 + 64; ++i)
            s = fmaf(pl[i], k_w[i * 64 + oc], s);
        s += __shfl_xor(s, 1);
        if (g == 0) keysT[(size_t)oc * Bn + b] = s;
    }
}

// ---- qk: 2 queries per block; float4 keysT loads ----
__global__ __launch_bounds__(128)
void qk_kernel(const float* __restrict__ pooled, const int* __restrict__ idx,
               const float* __restrict__ q_w, const float* __restrict__ q_b,
               const float* __restrict__ keysT, float* __restrict__ out, int B, int N)
{
    const int n0 = blockIdx.x * 2, t = threadIdx.x;
    const int n1 = n0 + 1;
    const bool has1 = (n1 < N);
    __shared__ float p0[128], p1[128];
    __shared__ float q0[64], q1[64];
    const int bi0 = idx[n0];
    const int bi1 = has1 ? idx[n1] : bi0;
    p0[t] = pooled[(size_t)bi0 * 128 + t];
    p1[t] = pooled[(size_t)bi1 * 128 + t];
    __syncthreads();
    if (t < 64) {
        float s = q_b[t];
#pragma unroll
        for (int i = 0; i < 128; ++i) s = fmaf(p0[i], q_w[i * 64 + t], s);
        q0[t] = s;
    } else {
        const int tt = t - 64;
        float s = q_b[tt];
#pragma unroll
        for (int i = 0; i < 128; ++i) s = fmaf(p1[i], q_w[i * 64 + tt], s);
        q1[tt] = s;
    }
    __syncthreads();
    for (int m0 = t * 4; m0 < B; m0 += 512) {
        f32x4 a0 = {0.f, 0.f, 0.f, 0.f}, a1 = {0.f, 0.f, 0.f, 0.f};
#pragma unroll 8
        for (int i = 0; i < 64; ++i) {
            const float4 kv = *(const float4*)&keysT[(size_t)i * B + m0];
            const float qa = q0[i], qb = q1[i];
            a0[0] = fmaf(qa, kv.x, a0[0]); a0[1] = fmaf(qa, kv.y, a0[1]);
            a0[2] = fmaf(qa, kv.z, a0[2]); a0[3] = fmaf(qa, kv.w, a0[3]);
            a1[0] = fmaf(qb, kv.x, a1[0]); a1[1] = fmaf(qb, kv.y, a1[1]);
            a1[2] = fmaf(qb, kv.z, a1[2]); a1[3] = fmaf(qb, kv.w, a1[3]);
        }
        *(f32x4*)&out[(size_t)n0 * B + m0] = a0;
        if (has1) *(f32x4*)&out[(size_t)n1 * B + m0] = a1;
    }
}

// ============================ LAUNCH ============================

extern "C" void kernel_launch(void* const* d_in, const int* in_sizes, int n_in,
                              void* d_out, int out_size, void* d_ws, size_t ws_size,
                              hipStream_t stream)
{
    const float* reads      = (const float*)d_in[0];
    const int*   idx        = (const int*)d_in[1];
    const float* exp_w      = (const float*)d_in[2];
    const float* exp_b      = (const float*)d_in[3];
    const float* in_proj_w  = (const float*)d_in[4];
    const float* conv_w     = (const float*)d_in[5];
    const float* conv_b     = (const float*)d_in[6];
    const float* x_proj_w   = (const float*)d_in[7];
    const float* dt_w       = (const float*)d_in[8];
    const float* dt_b       = (const float*)d_in[9];
    const float* A_log      = (const float*)d_in[10];
    const float* D_skip     = (const float*)d_in[11];
    const float* out_proj_w = (const float*)d_in[12];
    const float* q_w        = (const float*)d_in[13];
    const float* q_b        = (const float*)d_in[14];
    const float* k_w        = (const float*)d_in[15];
    const float* k_b        = (const float*)d_in[16];

    const int B = in_sizes[0] / (L_SEQ * 4);
    const int N = in_sizes[1];

    char* wsb = (char*)d_ws;
    size_t off = 0;
    auto alloc = [&](size_t bytes) {
        size_t o = off;
        off = (off + bytes + 255) & ~(size_t)255;
        return o;
    };

    float*     pooled = (float*)(wsb + alloc((size_t)B * 128 * 4));
    float*     keysT  = (float*)(wsb + alloc((size_t)B * 64 * 4));
    _Float16*  WT     = (_Float16*)(wsb + alloc(160 * 128 * 2));
    _Float16*  W2     = (_Float16*)(wsb + alloc(256 * 32 * 2));
    float*     bias2  = (float*)(wsb + alloc(128 * 4));
    int*       sflag  = (int*)(wsb + alloc(256));

    const size_t pairs = (size_t)B * NSEG * 8 * 128;
    f16x2* Qg = (f16x2*)(wsb + alloc(pairs * 4));
    f16x2* Pg = (f16x2*)(wsb + alloc(pairs * 4));
    f16x2* Kg = (f16x2*)(wsb + alloc(pairs * 4));
    float* GS = (float*)(wsb + alloc((size_t)B * NSEG * 128 * 4));
    float* CZ = (float*)(wsb + alloc((size_t)B * 16 * 128 * 4));
    float* SL = (float*)(wsb + alloc((size_t)B * 128 * 4));

    k_prep<<<7, 256, 0, stream>>>(exp_w, exp_b, in_proj_w, x_proj_w, dt_w,
                                  conv_w, conv_b, A_log, WT, W2, bias2, sflag);
    mamba_seg<<<B * NSEG, 256, 0, stream>>>(reads, WT, W2, bias2, dt_b,
                                            A_log, D_skip, sflag, Qg, Pg, Kg,
                                            GS, CZ, SL, B);
    stitch<NSEG><<<B, 256, 0, stream>>>(Qg, Pg, Kg, GS, CZ, SL, out_proj_w, k_w, k_b,
                                        pooled, keysT, B);
    qk_kernel<<<(N + 1) / 2, 128, 0, stream>>>(pooled, idx, q_w, q_b, keysT,
                                               (float*)d_out, B, N);
}

// Round 17
// 121.578 us; speedup vs baseline: 2.5674x; 1.0358x over previous
//
#include <hip/hip_runtime.h>
#include <math.h>

#define L_SEQ 256
#define TILE 16
#define NSEG 16

typedef __attribute__((ext_vector_type(2))) float f32x2;
typedef __attribute__((ext_vector_type(4))) float f32x4;
typedef __attribute__((ext_vector_type(8))) _Float16 f16x8;
typedef __attribute__((ext_vector_type(4))) _Float16 f16x4;
typedef __attribute__((ext_vector_type(2))) _Float16 f16x2;

__device__ __forceinline__ f32x2 fma2(f32x2 a, f32x2 b, f32x2 c) {
    return __builtin_elementwise_fma(a, b, c);
}
__device__ __forceinline__ f32x2 splat2(float x) { f32x2 v = {x, x}; return v; }
__device__ __forceinline__ float rcp_f(float x) {
#if __has_builtin(__builtin_amdgcn_rcpf)
    return __builtin_amdgcn_rcpf(x);
#else
    return 1.f / x;
#endif
}
__device__ __forceinline__ float silu_f(float x) { return x * rcp_f(1.f + __expf(-x)); }

// ---- prep (one launch, 7 blocks):
//  blocks 0..4: WT[160][128] f16 = [x_proj[:,:4]@dt_w | x_proj[:,4:36]]^T
//  block 5:     W2[256][32] f16 (conv+expansion+in_proj folded) + bias2
//  block 6:     sflag = all channels have A[n] == -(n+1)
__global__ __launch_bounds__(256)
void k_prep(const float* __restrict__ exp_w, const float* __restrict__ exp_b,
            const float* __restrict__ in_proj_w, const float* __restrict__ x_proj_w,
            const float* __restrict__ dt_w,
            const float* __restrict__ conv_w, const float* __restrict__ conv_b,
            const float* __restrict__ A_log,
            _Float16* __restrict__ WT, _Float16* __restrict__ W2,
            float* __restrict__ bias2, int* __restrict__ sflag)
{
    const int t = threadIdx.x, blk = blockIdx.x;
    if (blk < 5) {
        const int base = blk * 4096;
        for (int i = base + t; i < base + 4096; i += 256) {
            const int row = i >> 7, k = i & 127;
            float v;
            if (row < 128) {
                v = x_proj_w[k * 36 + 0] * dt_w[row]
                  + x_proj_w[k * 36 + 1] * dt_w[128 + row]
                  + x_proj_w[k * 36 + 2] * dt_w[256 + row]
                  + x_proj_w[k * 36 + 3] * dt_w[384 + row];
            } else {
                v = x_proj_w[k * 36 + 4 + (row - 128)];
            }
            WT[i] = (_Float16)v;
        }
    } else if (blk == 5) {
        // thread t<128 -> xc channel d=t ; t>=128 -> z channel d=t-128
        const int d = t & 127;
        const int col = (t < 128) ? d : (128 + d);
        float w0 = 0, w1 = 0, w2 = 0, w3 = 0, bb = 0;
        for (int k = 0; k < 64; ++k) {
            float w = in_proj_w[k * 256 + col];
            w0 = fmaf(exp_w[k], w, w0);
            w1 = fmaf(exp_w[64 + k], w, w1);
            w2 = fmaf(exp_w[128 + k], w, w2);
            w3 = fmaf(exp_w[192 + k], w, w3);
            bb = fmaf(exp_b[k], w, bb);
        }
        const float wx[4] = {w0, w1, w2, w3};
        if (t < 128) {
            for (int j = 0; j < 32; ++j) {
                float v = 0.f;
                if (j < 16)      v = conv_w[d * 4 + (j >> 2)] * wx[j & 3];
                else if (j < 20) v = conv_w[d * 4 + (j - 16)] * bb;
                W2[d * 32 + j] = (_Float16)v;
            }
            bias2[d] = conv_b[d];
        } else {
            for (int j = 0; j < 32; ++j) {
                float v = 0.f;
                if (j >= 12 && j < 16) v = wx[j - 12];
                else if (j == 19)      v = bb;
                W2[(128 + d) * 32 + j] = (_Float16)v;
            }
        }
    } else {
        __shared__ int ok;
        if (t == 0) ok = 1;
        __syncthreads();
        bool good = true;
        for (int i = t; i < 2048; i += 256) {
            float a = -__expf(A_log[i]);
            good = good && (fabsf(a + (float)((i & 15) + 1)) < 1e-3f);
        }
        if (!good) atomicAnd(&ok, 0);
        __syncthreads();
        if (t == 0) sflag[0] = ok;
    }
}

// ---- fused Mamba: grid = B*16 blocks x 256 threads, one 16-step segment each ----
// Summaries: Qg8/Kg8 packed f16x8 (4 pairs/b128); P as scalar Rg (f32) in
// structured mode (P[n] = R^(n+1)), full Pg8 only on the generic path.
__global__ __launch_bounds__(256, 8)
void mamba_seg(const float* __restrict__ reads,
               const _Float16* __restrict__ WT, const _Float16* __restrict__ W2,
               const float* __restrict__ bias2, const float* __restrict__ dt_b,
               const float* __restrict__ A_log, const float* __restrict__ D_skip,
               const int* __restrict__ sflag,
               f16x8* __restrict__ Qg8, f16x8* __restrict__ Pg8, f16x8* __restrict__ Kg8,
               float* __restrict__ Rg,
               float* __restrict__ GS, float* __restrict__ CZ, float* __restrict__ SL,
               int Bn)
{
    const int bx = blockIdx.x;
    const int b = bx >> 4, sidx = bx & 15;
    const int l_off = sidx * TILE;
    const int t = threadIdx.x;
    const int dd = t >> 1, g = t & 1;          // phase E: channel, state-half

    __shared__ __align__(16) _Float16 F[TILE * 40];    // features, K-padded
    __shared__ __align__(16) _Float16 XC[TILE * 136];  // conv out (silu), MFMA A
    __shared__ __align__(8)  f16x2    DR[TILE * 130];  // {delta, r}, padded stride
    __shared__ _Float16               ZS[TILE * 132];  // silu(z), padded stride
    __shared__ __align__(16) float    BC[TILE * 32];   // B(16)|C(16) per step

    const float dskip = D_skip[dd];
    const bool structured = (sflag[0] != 0);

    // ---- build F[16][40]: taps(16) | bias indicators(4) | pad ----
    for (int i = t; i < TILE * 40; i += 256) {
        const int l = i / 40, j = i - l * 40;
        _Float16 v = (_Float16)0.f;
        if (j < 16) {
            const int row = l_off + l - 3 + (j >> 2);
            if (row >= 0) v = (_Float16)reads[((size_t)b * L_SEQ + row) * 4 + (j & 3)];
        } else if (j < 20) {
            v = (l_off + l - 3 + (j - 16) >= 0) ? (_Float16)1.f : (_Float16)0.f;
        }
        F[i] = v;
    }
    __syncthreads();

    const int lane = t & 63, wv = t >> 6;
    const int fcol = lane & 15, kq = lane >> 4, rbase = kq * 4;

    // ---- phase A: MFMA [16 x 256] = F[16x32] @ W2^T ; silu -> XC | ZS ----
#pragma unroll
    for (int i = 0; i < 4; ++i) {
        const int n = wv + 4 * i;              // 16 tasks over 4 waves
        f16x8 af = *(const f16x8*)&F[fcol * 40 + kq * 8];
        f16x8 bf = *(const f16x8*)&W2[(n * 16 + fcol) * 32 + kq * 8];
        f32x4 acc = {0.f, 0.f, 0.f, 0.f};
        acc = __builtin_amdgcn_mfma_f32_16x16x32_f16(af, bf, acc, 0, 0, 0);
        if (n < 8) {
            const int ch = n * 16 + fcol;
            const float bv = bias2[ch];
#pragma unroll
            for (int r = 0; r < 4; ++r)
                XC[(rbase + r) * 136 + ch] = (_Float16)silu_f(acc[r] + bv);
        } else {
            const int ch = (n - 8) * 16 + fcol;
#pragma unroll
            for (int r = 0; r < 4; ++r)
                ZS[(rbase + r) * 132 + ch] = (_Float16)silu_f(acc[r]);
        }
    }
    __syncthreads();

    // ---- phase C: MFMA [16 x 160] = XC @ WT^T -> DR {softplus, sigmoid} | BC ----
#pragma unroll
    for (int i = 0; i < 3; ++i) {
        const int n = wv + 4 * i;              // 10 tasks over 4 waves
        if (n < 10) {
            f32x4 acc = {0.f, 0.f, 0.f, 0.f};
#pragma unroll
            for (int ks = 0; ks < 4; ++ks) {
                const int ko = ks * 32 + kq * 8;
                f16x8 xa = *(const f16x8*)&XC[fcol * 136 + ko];
                f16x8 bf = *(const f16x8*)&WT[(n * 16 + fcol) * 128 + ko];
                acc = __builtin_amdgcn_mfma_f32_16x16x32_f16(xa, bf, acc, 0, 0, 0);
            }
            if (n < 8) {
                const int ch = n * 16 + fcol;
                const float db = dt_b[ch];
#pragma unroll
                for (int r = 0; r < 4; ++r) {
                    const float dtr = fminf(acc[r] + db, 80.f);
                    const float ex = __expf(dtr);            // e^dtr (finite)
                    const float opx = 1.f + ex;
                    const float de = __logf(opx);            // softplus(dtr)
                    const float rr = rcp_f(opx);             // exp(-de)
                    DR[(rbase + r) * 130 + ch] = (f16x2){(_Float16)de, (_Float16)rr};
                }
            } else {
                const int jb = (n - 8) * 16 + fcol;
#pragma unroll
                for (int r = 0; r < 4; ++r)
                    BC[(rbase + r) * 32 + jb] = acc[r];
            }
        }
    }
    __syncthreads();

    // ---- phase E: 16-step serial scan; 2 lanes/channel, shuffle-free steps ----
    f32x2 h2[4], P2[4], K2[4];
#pragma unroll
    for (int k = 0; k < 4; ++k) { h2[k] = splat2(0.f); P2[k] = splat2(1.f); K2[k] = splat2(0.f); }
    f32x2 gs2 = splat2(0.f);
    float xz = 0.f;
    {
        auto scan_loop = [&](bool needpk) {
            for (int l = 0; l < TILE; ++l) {
                const f16x2 dz = DR[l * 130 + dd];
                const float de = (float)dz[0];
                const float rr = (float)dz[1];
                const float zs = (float)ZS[l * 132 + dd];
                const float xc = (float)XC[l * 136 + dd];
                const float du = de * xc;
                f32x2 E2[4];
                if (structured) {              // states 8g+1..8g+8: powers of r
                    const float r2 = rr * rr;
                    const float r4 = r2 * r2;
                    const float t1 = g ? (r4 * r4 * rr) : rr;   // r^(8g+1)
                    E2[0] = (f32x2){t1, t1 * rr};
                    const f32x2 r2s = splat2(r2);
                    E2[1] = E2[0] * r2s;
                    E2[2] = E2[1] * r2s;
                    E2[3] = E2[2] * r2s;
                } else {                       // cold generic path
#pragma unroll
                    for (int k = 0; k < 4; ++k) {
                        float e0 = exp2f(de * (-__expf(A_log[dd * 16 + g * 8 + 2 * k])) * 1.44269504f);
                        float e1 = exp2f(de * (-__expf(A_log[dd * 16 + g * 8 + 2 * k + 1])) * 1.44269504f);
                        E2[k] = (f32x2){e0, e1};
                    }
                }
                const float4 Bq0 = *(const float4*)&BC[l * 32 + g * 8];
                const float4 Bq1 = *(const float4*)&BC[l * 32 + g * 8 + 4];
                const float4 Cq0 = *(const float4*)&BC[l * 32 + 16 + g * 8];
                const float4 Cq1 = *(const float4*)&BC[l * 32 + 16 + g * 8 + 4];
                const f32x2 B2[4] = {{Bq0.x, Bq0.y}, {Bq0.z, Bq0.w}, {Bq1.x, Bq1.y}, {Bq1.z, Bq1.w}};
                const f32x2 C2[4] = {{Cq0.x, Cq0.y}, {Cq0.z, Cq0.w}, {Cq1.x, Cq1.y}, {Cq1.z, Cq1.w}};
                const f32x2 dus = splat2(du), zss = splat2(zs);
                f32x2 yp2 = splat2(0.f);
#pragma unroll
                for (int k = 0; k < 4; ++k) {
                    h2[k] = fma2(E2[k], h2[k], dus * B2[k]);
                    yp2 = fma2(h2[k], C2[k], yp2);
                    if (needpk) {
                        P2[k] = P2[k] * E2[k];
                        K2[k] = fma2(zss, C2[k] * P2[k], K2[k]);
                    }
                }
                gs2 = fma2(yp2, zss, gs2);     // per-lane partial
                xz = fmaf(xc, zs, xz);         // skip-term partial
            }
        };
        if (sidx == 0) scan_loop(false);
        else           scan_loop(true);
    }

    // ---- segment summary writeout (packed b128; P as scalar R when structured) ----
    {
        const size_t sb = (size_t)sidx * Bn + b;
        const size_t rowq = (sb * 2 + g) * 128 + dd;
        f16x8 qv;
#pragma unroll
        for (int k = 0; k < 4; ++k) {
            qv[2 * k]     = (_Float16)h2[k].x;
            qv[2 * k + 1] = (_Float16)h2[k].y;
        }
        Qg8[rowq] = qv;
        if (sidx != 0) {
            f16x8 kv;
#pragma unroll
            for (int k = 0; k < 4; ++k) {
                kv[2 * k]     = (_Float16)K2[k].x;
                kv[2 * k + 1] = (_Float16)K2[k].y;
            }
            Kg8[rowq] = kv;
            if (structured) {
                if (g == 0) Rg[sb * 128 + dd] = P2[0].x;   // R = prod(r); P[n]=R^(n+1)
            } else {
                f16x8 pv;
#pragma unroll
                for (int k = 0; k < 4; ++k) {
                    pv[2 * k]     = (_Float16)P2[k].x;
                    pv[2 * k + 1] = (_Float16)P2[k].y;
                }
                Pg8[rowq] = pv;
            }
        }
        float gsp = gs2.x + gs2.y;
        gsp += __shfl_xor(gsp, 1);             // combine lane partials once
        const float gsum = fmaf(dskip, xz, gsp);
        if (g == 0) GS[sb * 128 + dd] = gsum;
        if (sidx == NSEG - 1) {
            const float zs_last = (float)ZS[(TILE - 1) * 132 + dd];
            const float xc_last = (float)XC[(TILE - 1) * 136 + dd];
#pragma unroll
            for (int k = 0; k < 8; ++k)
                CZ[((size_t)b * 16 + g * 8 + k) * 128 + dd] =
                    zs_last * BC[(TILE - 1) * 32 + 16 + g * 8 + k];
            if (g == 0) SL[(size_t)b * 128 + dd] = zs_last * xc_last * dskip;
        }
    }
}

// ---- stitch: 256 threads; packed summaries; P rebuilt from scalar R ----
template<int NS>
__global__ __launch_bounds__(256)
void stitch(const f16x8* __restrict__ Qg8, const f16x8* __restrict__ Pg8,
            const f16x8* __restrict__ Kg8, const float* __restrict__ Rg,
            const float* __restrict__ GS,
            const float* __restrict__ CZ, const float* __restrict__ SL,
            const int* __restrict__ sflag,
            const float* __restrict__ out_proj_w,
            const float* __restrict__ k_w, const float* __restrict__ k_b,
            float* __restrict__ pooled, float* __restrict__ keysT, int Bn)
{
    const int b = blockIdx.x, t = threadIdx.x;
    const int d = t >> 1, g = t & 1;
    const bool structured = (sflag[0] != 0);
    __shared__ float gb[256];
    __shared__ float pl[128];

    float h[8];                                    // states 8g..8g+7
    float gsum = (g == 0) ? GS[(size_t)b * 128 + d] : 0.f;
    {
        f16x8 qv = Qg8[((size_t)b * 2 + g) * 128 + d];    // s = 0: h0 = 0
#pragma unroll
        for (int j = 0; j < 8; ++j) h[j] = (float)qv[j];
    }
#pragma unroll
    for (int s = 1; s < NS; ++s) {
        const size_t sb = (size_t)s * Bn + b;
        if (g == 0) gsum += GS[sb * 128 + d];
        const size_t rowq = (sb * 2 + g) * 128 + d;
        const f16x8 qv = Qg8[rowq];
        const f16x8 kv = Kg8[rowq];
        float P[8];
        if (structured) {
            const float R = Rg[sb * 128 + d];
            const float R2 = R * R;
            float t1 = R;
            if (g) { const float R4 = R2 * R2; t1 = R4 * R4 * R; }  // R^(8g+1)
            P[0] = t1;
#pragma unroll
            for (int j = 1; j < 8; ++j) P[j] = P[j - 1] * R;
        } else {
            const f16x8 pv = Pg8[rowq];
#pragma unroll
            for (int j = 0; j < 8; ++j) P[j] = (float)pv[j];
        }
        float corr = 0.f;
#pragma unroll
        for (int j = 0; j < 8; ++j) {
            corr = fmaf((float)kv[j], h[j], corr);
            h[j] = fmaf(P[j], h[j], (float)qv[j]);
        }
        gsum += corr;
    }
    float glast = (g == 0) ? SL[(size_t)b * 128 + d] : 0.f;
#pragma unroll
    for (int k = 0; k < 8; ++k)
        glast = fmaf(CZ[((size_t)b * 16 + g * 8 + k) * 128 + d], h[k], glast);

    gsum += __shfl_xor(gsum, 1);
    glast += __shfl_xor(glast, 1);
    if (g == 0) { gb[d] = gsum * (1.f / (float)L_SEQ); gb[128 + d] = glast; }
    __syncthreads();

    // out_proj: 128 outputs x 2 threads each
    {
        const int oi = t >> 1;                 // 0..127
        const int half = oi >> 6, oc = oi & 63;
        const float* gbp = &gb[half * 128];
        float s = 0.f;
#pragma unroll 16
        for (int i = g * 64; i < g * 64 + 64; ++i)
            s = fmaf(gbp[i], out_proj_w[i * 64 + oc], s);
        s += __shfl_xor(s, 1);
        if (g == 0) { pooled[(size_t)b * 128 + oi] = s; pl[oi] = s; }
    }
    __syncthreads();

    // keys: 64 outputs x 2 threads each
    if (t < 128) {
        const int oc = t >> 1;
        float s = (g == 0) ? k_b[oc] : 0.f;
#pragma unroll 16
        for (int i = g * 64; i < g * 64 + 64; ++i)
            s = fmaf(pl[i], k_w[i * 64 + oc], s);
        s += __shfl_xor(s, 1);
        if (g == 0) keysT[(size_t)oc * Bn + b] = s;
    }
}

// ---- qk: 2 queries per block; float4 keysT loads ----
__global__ __launch_bounds__(128)
void qk_kernel(const float* __restrict__ pooled, const int* __restrict__ idx,
               const float* __restrict__ q_w, const float* __restrict__ q_b,
               const float* __restrict__ keysT, float* __restrict__ out, int B, int N)
{
    const int n0 = blockIdx.x * 2, t = threadIdx.x;
    const int n1 = n0 + 1;
    const bool has1 = (n1 < N);
    __shared__ float p0[128], p1[128];
    __shared__ float q0[64], q1[64];
    const int bi0 = idx[n0];
    const int bi1 = has1 ? idx[n1] : bi0;
    p0[t] = pooled[(size_t)bi0 * 128 + t];
    p1[t] = pooled[(size_t)bi1 * 128 + t];
    __syncthreads();
    if (t < 64) {
        float s = q_b[t];
#pragma unroll
        for (int i = 0; i < 128; ++i) s = fmaf(p0[i], q_w[i * 64 + t], s);
        q0[t] = s;
    } else {
        const int tt = t - 64;
        float s = q_b[tt];
#pragma unroll
        for (int i = 0; i < 128; ++i) s = fmaf(p1[i], q_w[i * 64 + tt], s);
        q1[tt] = s;
    }
    __syncthreads();
    for (int m0 = t * 4; m0 < B; m0 += 512) {
        f32x4 a0 = {0.f, 0.f, 0.f, 0.f}, a1 = {0.f, 0.f, 0.f, 0.f};
#pragma unroll 8
        for (int i = 0; i < 64; ++i) {
            const float4 kv = *(const float4*)&keysT[(size_t)i * B + m0];
            const float qa = q0[i], qb = q1[i];
            a0[0] = fmaf(qa, kv.x, a0[0]); a0[1] = fmaf(qa, kv.y, a0[1]);
            a0[2] = fmaf(qa, kv.z, a0[2]); a0[3] = fmaf(qa, kv.w, a0[3]);
            a1[0] = fmaf(qb, kv.x, a1[0]); a1[1] = fmaf(qb, kv.y, a1[1]);
            a1[2] = fmaf(qb, kv.z, a1[2]); a1[3] = fmaf(qb, kv.w, a1[3]);
        }
        *(f32x4*)&out[(size_t)n0 * B + m0] = a0;
        if (has1) *(f32x4*)&out[(size_t)n1 * B + m0] = a1;
    }
}

// ============================ LAUNCH ============================

extern "C" void kernel_launch(void* const* d_in, const int* in_sizes, int n_in,
                              void* d_out, int out_size, void* d_ws, size_t ws_size,
                              hipStream_t stream)
{
    const float* reads      = (const float*)d_in[0];
    const int*   idx        = (const int*)d_in[1];
    const float* exp_w      = (const float*)d_in[2];
    const float* exp_b      = (const float*)d_in[3];
    const float* in_proj_w  = (const float*)d_in[4];
    const float* conv_w     = (const float*)d_in[5];
    const float* conv_b     = (const float*)d_in[6];
    const float* x_proj_w   = (const float*)d_in[7];
    const float* dt_w       = (const float*)d_in[8];
    const float* dt_b       = (const float*)d_in[9];
    const float* A_log      = (const float*)d_in[10];
    const float* D_skip     = (const float*)d_in[11];
    const float* out_proj_w = (const float*)d_in[12];
    const float* q_w        = (const float*)d_in[13];
    const float* q_b        = (const float*)d_in[14];
    const float* k_w        = (const float*)d_in[15];
    const float* k_b        = (const float*)d_in[16];

    const int B = in_sizes[0] / (L_SEQ * 4);
    const int N = in_sizes[1];

    char* wsb = (char*)d_ws;
    size_t off = 0;
    auto alloc = [&](size_t bytes) {
        size_t o = off;
        off = (off + bytes + 255) & ~(size_t)255;
        return o;
    };

    float*     pooled = (float*)(wsb + alloc((size_t)B * 128 * 4));
    float*     keysT  = (float*)(wsb + alloc((size_t)B * 64 * 4));
    _Float16*  WT     = (_Float16*)(wsb + alloc(160 * 128 * 2));
    _Float16*  W2     = (_Float16*)(wsb + alloc(256 * 32 * 2));
    float*     bias2  = (float*)(wsb + alloc(128 * 4));
    int*       sflag  = (int*)(wsb + alloc(256));

    const size_t rows8 = (size_t)B * NSEG * 2 * 128;   // f16x8 elements
    f16x8* Qg8 = (f16x8*)(wsb + alloc(rows8 * 16));
    f16x8* Kg8 = (f16x8*)(wsb + alloc(rows8 * 16));
    f16x8* Pg8 = (f16x8*)(wsb + alloc(rows8 * 16));    // generic path only
    float* Rg  = (float*)Pg8;                          // alias: structured path only
    float* GS  = (float*)(wsb + alloc((size_t)B * NSEG * 128 * 4));
    float* CZ  = (float*)(wsb + alloc((size_t)B * 16 * 128 * 4));
    float* SL  = (float*)(wsb + alloc((size_t)B * 128 * 4));

    k_prep<<<7, 256, 0, stream>>>(exp_w, exp_b, in_proj_w, x_proj_w, dt_w,
                                  conv_w, conv_b, A_log, WT, W2, bias2, sflag);
    mamba_seg<<<B * NSEG, 256, 0, stream>>>(reads, WT, W2, bias2, dt_b,
                                            A_log, D_skip, sflag,
                                            Qg8, Pg8, Kg8, Rg,
                                            GS, CZ, SL, B);
    stitch<NSEG><<<B, 256, 0, stream>>>(Qg8, Pg8, Kg8, Rg, GS, CZ, SL, sflag,
                                        out_proj_w, k_w, k_b, pooled, keysT, B);
    qk_kernel<<<(N + 1) / 2, 128, 0, stream>>>(pooled, idx, q_w, q_b, keysT,
                                               (float*)d_out, B, N);
}